// Round 3
// baseline (115.464 us; speedup 1.0000x reference)
//
#include <hip/hip_runtime.h>
#include <math.h>

// ---------------------------------------------------------------------------
// QCNN_Diff R12: 4 elements per 16-lane group (ILP x2 over R9).
// Evidence: R10 (more waves) null, R11 (code grouping) null, R8->R9 (ILP x2)
// = +70% throughput. The kernel is issue-stalled (VALUBusy 37% == measured
// floor arithmetic) and only per-wave ILP has ever moved it.
// w[64] = four interleaved elements; slot-pair bits = low 4 index bits,
// element = bits 4-5, so i|(1<<SB) (SB in 0..3) stays in-element.
// Shared across all 4 elements: SGPR matrix setup, rz phase coefficients and
// the 16 rz __sincosf calls. Waves halve (2048), per-wave instrs ~1.9x.
// __launch_bounds__(256,1) so the compiler can use up to 512 VGPRs (no spill);
// grid (512 blocks) gives 2 waves/SIMD regardless, which R10 proved is enough.
// Math byte-identical to validated R9 (absmax 0.0); loops 32->64, e-loops 2->4.
// slot bits: q3->S0 q7->S1 q5->S2 q1->S3; lane bits: q0->L0 q2->L1 q4->L2 q6->L3
// ---------------------------------------------------------------------------

typedef float v2f __attribute__((ext_vector_type(2)));

__device__ __forceinline__ v2f mk2(float a, float b) { v2f r; r.x = a; r.y = b; return r; }
__device__ __forceinline__ v2f ld2(const float* __restrict__ p) { return *(const v2f*)p; }

// ---- VOP3P primitives, VGPR x VGPR -----------------------------------------
__device__ __forceinline__ v2f pk_mul_s(v2f a, v2f b) { v2f d;
  asm("v_pk_mul_f32 %0, %1, %2 op_sel:[0,0] op_sel_hi:[0,1]" : "=v"(d) : "v"(a), "v"(b)); return d; }
__device__ __forceinline__ v2f pk_fma_irot(v2f a, v2f b, v2f c) { v2f d;
  asm("v_pk_fma_f32 %0, %1, %2, %3 op_sel:[1,1,0] op_sel_hi:[1,0,1] neg_lo:[0,1,0]" : "=v"(d) : "v"(a), "v"(b), "v"(c)); return d; }
__device__ __forceinline__ v2f cmul(v2f a, v2f b) { return pk_fma_irot(a, b, pk_mul_s(a, b)); }
__device__ __forceinline__ v2f pk_mul_swap(v2f a, v2f b) { v2f d;
  asm("v_pk_mul_f32 %0, %1, %2 op_sel:[1,0] op_sel_hi:[0,1]" : "=v"(d) : "v"(a), "v"(b)); return d; }

// ---- VOP3P primitives, SGPR (wave-uniform) first operand -------------------
__device__ __forceinline__ v2f pk_mul_sM(v2f M, v2f b) { v2f d;
  asm("v_pk_mul_f32 %0, %1, %2 op_sel:[0,0] op_sel_hi:[0,1]" : "=v"(d) : "s"(M), "v"(b)); return d; }
__device__ __forceinline__ v2f pk_fma_sloM(v2f M, v2f b, v2f c) { v2f d;
  asm("v_pk_fma_f32 %0, %1, %2, %3 op_sel:[0,0,0] op_sel_hi:[0,1,1]" : "=v"(d) : "s"(M), "v"(b), "v"(c)); return d; }
__device__ __forceinline__ v2f pk_fma_shiM(v2f M, v2f b, v2f c) { v2f d;
  asm("v_pk_fma_f32 %0, %1, %2, %3 op_sel:[1,0,0] op_sel_hi:[1,1,1]" : "=v"(d) : "s"(M), "v"(b), "v"(c)); return d; }
__device__ __forceinline__ v2f pk_fma_shi_negM(v2f M, v2f b, v2f c) { v2f d;
  asm("v_pk_fma_f32 %0, %1, %2, %3 op_sel:[1,0,0] op_sel_hi:[1,1,1] neg_lo:[1,0,0] neg_hi:[1,0,0]" : "=v"(d) : "s"(M), "v"(b), "v"(c)); return d; }
__device__ __forceinline__ v2f pk_fma_rotM(v2f M, v2f b, v2f c) { v2f d;
  asm("v_pk_fma_f32 %0, %1, %2, %3 op_sel:[1,1,0] op_sel_hi:[1,0,1] neg_hi:[0,1,0]" : "=v"(d) : "s"(M), "v"(b), "v"(c)); return d; }
__device__ __forceinline__ v2f pk_fma_irotM(v2f M, v2f b, v2f c) { v2f d;
  asm("v_pk_fma_f32 %0, %1, %2, %3 op_sel:[1,1,0] op_sel_hi:[1,0,1] neg_lo:[0,1,0]" : "=v"(d) : "s"(M), "v"(b), "v"(c)); return d; }

template <int MASK>
__device__ __forceinline__ float swz1(float v) {
  constexpr int pat = (MASK << 10) | 0x1F;  // xor-mode
  return __int_as_float(__builtin_amdgcn_ds_swizzle(__float_as_int(v), pat));
}
template <int MASK>
__device__ __forceinline__ v2f swz2(v2f v) {
  v2f r; r.x = swz1<MASK>(v.x); r.y = swz1<MASK>(v.y); return r;
}

// ---- u3 row: ua*a + ub*b, matrices from SGPRs ------------------------------
template <bool A_REAL>
__device__ __forceinline__ v2f u3row_s(v2f ua, v2f ub, v2f a, v2f b) {
  v2f t = pk_mul_sM(ua, a);
  if constexpr (!A_REAL) t = pk_fma_irotM(ua, a, t);
  t = pk_fma_sloM(ub, b, t);
  return pk_fma_irotM(ub, b, t);
}

// All gate helpers operate on w[64] = four interleaved elements; slot-pair
// bits are the low 4 index bits, element = bits 4-5, so i|(1<<SB) stays
// in-element for SB in 0..3.
template <int SB>
__device__ __forceinline__ void u3_apply(v2f w[64], const float* __restrict__ p) {
  const v2f M0 = ld2(p), M1 = ld2(p + 2), M2 = ld2(p + 4), M3 = ld2(p + 6);
#pragma unroll
  for (int i = 0; i < 64; ++i) {
    if (i & (1 << SB)) continue;
    const int i1 = i | (1 << SB);
    const v2f a = w[i], b = w[i1];
    w[i] = u3row_s<true>(M0, M1, a, b);
    w[i1] = u3row_s<false>(M3, M2, b, a);
  }
}

template <int SB, int CB, bool M00R>
__device__ __forceinline__ void u3_sel(v2f w[64], const float* __restrict__ pM,
                                       const float* __restrict__ pN) {
  const v2f M0 = ld2(pM), M1 = ld2(pM + 2), M2 = ld2(pM + 4), M3 = ld2(pM + 6);
  const v2f N0 = ld2(pN), N1 = ld2(pN + 2), N2 = ld2(pN + 4), N3 = ld2(pN + 6);
#pragma unroll
  for (int i = 0; i < 64; ++i) {
    if (i & (1 << SB)) continue;
    const int i1 = i | (1 << SB);
    const v2f a = w[i], b = w[i1];
    if ((i >> CB) & 1) {
      w[i] = u3row_s<false>(N0, N1, a, b);
      w[i1] = u3row_s<false>(N3, N2, b, a);
    } else {
      w[i] = u3row_s<M00R>(M0, M1, a, b);
      w[i1] = u3row_s<false>(M3, M2, b, a);
    }
  }
}

template <int SB, int LB>
__device__ __forceinline__ void crx_Sc_Lt(v2f w[64], v2f cs) {
#pragma unroll
  for (int i = 0; i < 64; ++i) {
    if (!(i & (1 << SB))) continue;
    const v2f p = swz2<(1 << LB)>(w[i]);
    w[i] = pk_fma_rotM(cs, p, pk_mul_sM(cs, w[i]));
  }
}

template <int SB, int LB>
__device__ __forceinline__ void cr_ry_r(float w[64], v2f cs, int gl) {
  const bool tb = (gl >> LB) & 1;
  const float Ky = tb ? cs.y : -cs.y;
#pragma unroll
  for (int i = 0; i < 64; ++i) {
    if (!(i & (1 << SB))) continue;
    const float p = swz1<(1 << LB)>(w[i]);
    w[i] = __builtin_fmaf(Ky, p, cs.x * w[i]);
  }
}

template <int KIND, int SBc, int SBt>
__device__ __forceinline__ void cr_Sc_St(v2f w[64], v2f cs) {
#pragma unroll
  for (int i = 0; i < 64; ++i) {
    if (!(i & (1 << SBc))) continue;
    if constexpr (KIND == 2) {
      const v2f t = pk_mul_sM(cs, w[i]);
      w[i] = (i & (1 << SBt)) ? pk_fma_irotM(cs, w[i], t)
                              : pk_fma_rotM(cs, w[i], t);
    } else {
      if (i & (1 << SBt)) continue;
      const int i1 = i | (1 << SBt);
      const v2f a = w[i], b = w[i1];
      if constexpr (KIND == 0) {
        w[i] = pk_fma_rotM(cs, b, pk_mul_sM(cs, a));
        w[i1] = pk_fma_rotM(cs, a, pk_mul_sM(cs, b));
      } else {
        w[i] = pk_fma_shi_negM(cs, b, pk_mul_sM(cs, a));
        w[i1] = pk_fma_shiM(cs, a, pk_mul_sM(cs, b));
      }
    }
  }
}

template <int SB>
__device__ __forceinline__ void u3_lift(v2f w[64], const float wr[64],
                                        const float* __restrict__ p) {
  const v2f M0 = ld2(p), M1 = ld2(p + 2), M2 = ld2(p + 4), M3 = ld2(p + 6);
#pragma unroll
  for (int i = 0; i < 64; ++i) {
    if (i & (1 << SB)) continue;
    const int i1 = i | (1 << SB);
    const float a = wr[i], b = wr[i1];
    w[i] = mk2(__builtin_fmaf(a, M0.x, b * M1.x), b * M1.y);
    w[i1] = mk2(__builtin_fmaf(a, M2.x, b * M3.x),
                __builtin_fmaf(a, M2.y, b * M3.y));
  }
}

__device__ __forceinline__ void measure4(v2f w[64], const float* __restrict__ q,
                                         v2f res[4]) {
  const v2f qa = ld2(q);      // (alpha, beta)
  const v2f qg = ld2(q + 2);  // (gr, gi)
  float z3[4], z7[4];
#pragma unroll
  for (int e = 0; e < 4; ++e) {
    float z3a = 0.f, z3b = 0.f, z7p = 0.f, z7m = 0.f;
#pragma unroll
    for (int s0 = 0; s0 < 16; s0 += 2) {
      const v2f a = w[e * 16 + s0], b = w[e * 16 + s0 + 1];
      const v2f t1 = a * b, t2 = pk_mul_swap(a, b), t3 = a * a, t4 = b * b;
      const float r = t1.x + t1.y;
      const float m = t2.x - t2.y;
      const float na = t3.x + t3.y;
      const float nb = t4.x + t4.y;
      z3a = __builtin_fmaf(qa.x, na, z3a);
      z3b = __builtin_fmaf(qa.y, nb, z3b);
      z3a = __builtin_fmaf(qg.x, r, z3a);
      z3b = __builtin_fmaf(-qg.y, m, z3b);
      const float nn = na + nb;
      if (s0 & 2) z7m += nn; else z7p += nn;
    }
    z3[e] = z3a + z3b;
    z7[e] = z7p - z7m;
  }
#pragma unroll
  for (int e = 0; e < 4; ++e) { z3[e] += swz1<1>(z3[e]); z7[e] += swz1<1>(z7[e]); }
#pragma unroll
  for (int e = 0; e < 4; ++e) { z3[e] += swz1<2>(z3[e]); z7[e] += swz1<2>(z7[e]); }
#pragma unroll
  for (int e = 0; e < 4; ++e) { z3[e] += swz1<4>(z3[e]); z7[e] += swz1<4>(z7[e]); }
#pragma unroll
  for (int e = 0; e < 4; ++e) { z3[e] += swz1<8>(z3[e]); z7[e] += swz1<8>(z7[e]); }
#pragma unroll
  for (int e = 0; e < 4; ++e) res[e] = mk2(z3[e], z7[e]);
}

template <int KIND>
__device__ __forceinline__ void tail_common(v2f w[64], const float* __restrict__ Gb,
                                            v2f res[4]) {
  u3_sel<0, 3, true>(w, Gb + 72, Gb + 80);    // U3first(3) / R13.U3first(3)
  u3_apply<2>(w, Gb + 88);                    // U3(5)
  u3_sel<1, 2, false>(w, Gb + 96, Gb + 104);  // Uf7.U7 / Uf7.R57.U7
  cr_Sc_St<KIND, 0, 2>(w, ld2(Gb + 56));      // CR(3,5)
  measure4(w, Gb + 112, res);                 // folds U3final(3)
}

__device__ __forceinline__ void load_sincos(const float* __restrict__ xb,
                                            float sn[8], float cn[8]) {
  const float4 xlo = ((const float4*)xb)[0];
  const float4 xhi = ((const float4*)xb)[1];
  const float xq[8] = {xlo.x, xlo.y, xlo.z, xlo.w, xhi.x, xhi.y, xhi.z, xhi.w};
#pragma unroll
  for (int q = 0; q < 8; ++q) __sincosf(0.5f * xq[q], &sn[q], &cn[q]);
}

// ============================ branch heads ==================================
__device__ __forceinline__ void run_rx(const float* const xb[4],
                                       const float* __restrict__ Gb, int gl,
                                       v2f res[4]) {
  const bool l0 = gl & 1, l1 = (gl >> 1) & 1, l2 = (gl >> 2) & 1, l3 = (gl >> 3) & 1;
  v2f w[64];
#pragma unroll
  for (int e = 0; e < 4; ++e) {
    float sn[8], cn[8];
    load_sincos(xb[e], sn, cn);
    v2f pa[4], pb[4];
#pragma unroll
    for (int pr = 0; pr < 4; ++pr) {
      const bool lh = (pr == 0) ? l0 : (pr == 1) ? l1 : (pr == 2) ? l2 : l3;
      const float c = Gb[pr * 8], s = Gb[pr * 8 + 1];
      const float uc = lh ? sn[2 * pr] : cn[2 * pr];
      const float b0 = uc * cn[2 * pr + 1], b1 = uc * sn[2 * pr + 1];
      const float Kx = lh ? c : 1.f;
      const float Kyn = lh ? -s : 0.f;
      pa[pr] = mk2(Kx * b0, Kyn * b1);
      pb[pr] = mk2(Kx * b1, Kyn * b0);
    }
    v2f A[4] = {cmul(pa[0], pa[2]), cmul(pa[0], pb[2]), cmul(pb[0], pa[2]), cmul(pb[0], pb[2])};
    v2f Bv[4] = {cmul(pa[3], pa[1]), cmul(pa[3], pb[1]), cmul(pb[3], pa[1]), cmul(pb[3], pb[1])};
#pragma unroll
    for (int s = 0; s < 16; ++s) w[e * 16 + s] = cmul(A[s >> 2], Bv[s & 3]);
  }
  crx_Sc_Lt<3, 1>(w, ld2(Gb + 32));  // (1,2)
  crx_Sc_Lt<0, 2>(w, ld2(Gb + 40));  // (3,4)
  crx_Sc_Lt<2, 3>(w, ld2(Gb + 48));  // (5,6)
  u3_apply<3>(w, Gb + 64);           // U3(1)
  tail_common<0>(w, Gb, res);
}

__device__ __forceinline__ void run_ry(const float* const xb[4],
                                       const float* __restrict__ Gb, int gl,
                                       v2f res[4]) {
  const bool l0 = gl & 1, l1 = (gl >> 1) & 1, l2 = (gl >> 2) & 1, l3 = (gl >> 3) & 1;
  float wr[64];
#pragma unroll
  for (int e = 0; e < 4; ++e) {
    float sn[8], cn[8];
    load_sincos(xb[e], sn, cn);
    float pa[4], pb[4];
#pragma unroll
    for (int pr = 0; pr < 4; ++pr) {
      const bool lh = (pr == 0) ? l0 : (pr == 1) ? l1 : (pr == 2) ? l2 : l3;
      const float c = Gb[pr * 8], s = Gb[pr * 8 + 1];
      const float uc = lh ? sn[2 * pr] : cn[2 * pr];
      const float b0 = uc * cn[2 * pr + 1], b1 = uc * sn[2 * pr + 1];
      const float Kx = lh ? c : 1.f;
      const float Ky = lh ? s : 0.f;
      pa[pr] = Kx * b0 - Ky * b1;
      pb[pr] = Ky * b0 + Kx * b1;
    }
    const float A[4] = {pa[0] * pa[2], pa[0] * pb[2], pb[0] * pa[2], pb[0] * pb[2]};
    const float Bv[4] = {pa[3] * pa[1], pa[3] * pb[1], pb[3] * pa[1], pb[3] * pb[1]};
#pragma unroll
    for (int s = 0; s < 16; ++s) wr[e * 16 + s] = A[s >> 2] * Bv[s & 3];
  }
  cr_ry_r<3, 1>(wr, ld2(Gb + 32), gl);
  cr_ry_r<0, 2>(wr, ld2(Gb + 40), gl);
  cr_ry_r<2, 3>(wr, ld2(Gb + 48), gl);
  v2f w[64];
  u3_lift<3>(w, wr, Gb + 64);        // U3(1), real input
  tail_common<1>(w, Gb, res);
}

__device__ __forceinline__ void run_rz(const float* const xb[4],
                                       const float* __restrict__ Gb, int gl,
                                       v2f res[4]) {
  const bool l0 = gl & 1, l1 = (gl >> 1) & 1, l2 = (gl >> 2) & 1, l3 = (gl >> 3) & 1;
  // shared phase coefficients (element-independent)
  const float t0 = Gb[2], h0 = Gb[3];
  const float t1 = Gb[10], h1 = Gb[11];
  const float t2 = Gb[18], h2 = Gb[19];
  const float t3 = Gb[26], h3 = Gb[27];
  const float h4 = Gb[35], h5 = Gb[43], h6 = Gb[51];
  const float kk0 = (l1 ? t1 : 0.f) + (l2 ? h5 : -h5);
  const float kk1 = (l3 ? t3 : 0.f);
  const float kk2 = (l2 ? t2 : 0.f) + (l3 ? h6 : -h6);
  const float kk3 = (l0 ? t0 : 0.f) + (l1 ? h4 : -h4);
  const float aa = -((l0 ? h0 : 0.f) + (l1 ? h1 : 0.f) + (l2 ? h2 : 0.f) + (l3 ? h3 : 0.f));
  // per-element real envelopes
  float v01[4][4], v23[4][4];
#pragma unroll
  for (int e = 0; e < 4; ++e) {
    float sn[8], cn[8];
    load_sincos(xb[e], sn, cn);
    const float u0 = l0 ? sn[0] : cn[0];
    const float u2 = l1 ? sn[2] : cn[2];
    const float u4 = l2 ? sn[4] : cn[4];
    const float u6 = l3 ? sn[6] : cn[6];
    const float P = (u0 * u2) * (u4 * u6);
    v01[e][0] = P * (cn[3] * cn[7]); v01[e][1] = P * (sn[3] * cn[7]);
    v01[e][2] = P * (cn[3] * sn[7]); v01[e][3] = P * (sn[3] * sn[7]);
    v23[e][0] = cn[5] * cn[1]; v23[e][1] = sn[5] * cn[1];
    v23[e][2] = cn[5] * sn[1]; v23[e][3] = sn[5] * sn[1];
  }
  v2f w[64];
#pragma unroll
  for (int s = 0; s < 16; ++s) {
    float phv = aa;
    if (s & 1) phv += kk0;
    if (s & 2) phv += kk1;
    if (s & 4) phv += kk2;
    if (s & 8) phv += kk3;
    float sp, cp;
    __sincosf(phv, &sp, &cp);  // shared by all 4 elements
#pragma unroll
    for (int e = 0; e < 4; ++e) {
      const float ev = v01[e][s & 3] * v23[e][s >> 2];
      w[e * 16 + s] = mk2(ev * cp, ev * sp);
    }
  }
  u3_apply<3>(w, Gb + 64);           // U3(1)
  tail_common<2>(w, Gb, res);
}

// ============================ prep ==========================================
struct c2 { float r, i; };
__device__ __forceinline__ c2 cmulh(c2 a, c2 b) { return {a.r * b.r - a.i * b.i, a.r * b.i + a.i * b.r}; }
__device__ __forceinline__ c2 cmulc(c2 a, c2 b) { return {a.r * b.r + a.i * b.i, a.i * b.r - a.r * b.i}; }
__device__ __forceinline__ c2 caddh(c2 a, c2 b) { return {a.r + b.r, a.i + b.i}; }
__device__ void mat2mul(const c2 A[4], const c2 B[4], c2 C[4]) {
  C[0] = caddh(cmulh(A[0], B[0]), cmulh(A[1], B[2]));
  C[1] = caddh(cmulh(A[0], B[1]), cmulh(A[1], B[3]));
  C[2] = caddh(cmulh(A[2], B[0]), cmulh(A[3], B[2]));
  C[3] = caddh(cmulh(A[2], B[1]), cmulh(A[3], B[3]));
}
__device__ void u3m(const float* p, c2 M[4]) {
  float st, ct, sp, cp, sl, cl;
  sincosf(0.5f * p[0], &st, &ct);
  sincosf(p[1], &sp, &cp);
  sincosf(p[2], &sl, &cl);
  M[0] = {ct, 0.f};
  M[1] = {-cl * st, -sl * st};
  M[2] = {cp * st, sp * st};
  M[3] = {(cp * cl - sp * sl) * ct, (sp * cl + cp * sl) * ct};
}
__device__ void rmat(int kind, float th, c2 R[4]) {
  float s, c;
  sincosf(0.5f * th, &s, &c);
  if (kind == 0) { R[0] = {c, 0.f}; R[1] = {0.f, -s}; R[2] = {0.f, -s}; R[3] = {c, 0.f}; }
  else if (kind == 1) { R[0] = {c, 0.f}; R[1] = {-s, 0.f}; R[2] = {s, 0.f}; R[3] = {c, 0.f}; }
  else { R[0] = {c, -s}; R[1] = {0.f, 0.f}; R[2] = {0.f, 0.f}; R[3] = {c, s}; }
}
__device__ void storeM(float* dst, const c2 M[4]) {
#pragma unroll
  for (int j = 0; j < 4; ++j) { dst[2 * j] = M[j].r; dst[2 * j + 1] = M[j].i; }
}

__global__ void qcnn_prep(const float* __restrict__ crx, const float* __restrict__ u3x,
                          const float* __restrict__ cry, const float* __restrict__ u3y,
                          const float* __restrict__ crz, const float* __restrict__ u3z,
                          float* __restrict__ G) {
  const int br = threadIdx.x;
  if (br >= 3) return;
  const float* crp = (br == 0) ? crx : (br == 1) ? cry : crz;
  const float* u3p = (br == 0) ? u3x : (br == 1) ? u3y : u3z;
  float* Gb = G + br * 128;

  const int crIdx[8] = {0, 1, 2, 3, 4, 5, 6, 9};
#pragma unroll
  for (int i = 0; i < 8; ++i) {
    const float th = crp[crIdx[i]];
    float s, c;
    sincosf(0.5f * th, &s, &c);
    Gb[i * 8] = c;
    Gb[i * 8 + 1] = s;
    Gb[i * 8 + 2] = th;
    Gb[i * 8 + 3] = 0.5f * th;
  }
  c2 U1v[4], U3v[4], U5v[4], U7a[4], U7b[4], U3f[4], R[4], T[4], T2[4];
  u3m(u3p + 0, U1v);
  u3m(u3p + 3, U3v);
  u3m(u3p + 6, U5v);
  u3m(u3p + 9, U7a);
  u3m(u3p + 12, U3f);
  u3m(u3p + 15, U7b);
  storeM(Gb + 64, U1v);
  storeM(Gb + 72, U3v);
  rmat(br, crp[7], R);
  mat2mul(R, U3v, T);
  storeM(Gb + 80, T);
  storeM(Gb + 88, U5v);
  mat2mul(U7b, U7a, T);
  storeM(Gb + 96, T);
  rmat(br, crp[8], R);
  mat2mul(R, U7a, T);
  mat2mul(U7b, T, T2);
  storeM(Gb + 104, T2);
  const float n00 = U3f[0].r * U3f[0].r + U3f[0].i * U3f[0].i;
  const float n01 = U3f[1].r * U3f[1].r + U3f[1].i * U3f[1].i;
  const float n10 = U3f[2].r * U3f[2].r + U3f[2].i * U3f[2].i;
  const float n11 = U3f[3].r * U3f[3].r + U3f[3].i * U3f[3].i;
  const c2 g01 = cmulc(U3f[0], U3f[1]);
  const c2 g23 = cmulc(U3f[2], U3f[3]);
  Gb[112] = n00 - n10;
  Gb[113] = n01 - n11;
  Gb[114] = 2.f * (g01.r - g23.r);
  Gb[115] = 2.f * (g01.i - g23.i);
}

// ============================ main ==========================================
__global__ __launch_bounds__(256, 1) void qcnn_main(
    const float* __restrict__ x, const float* __restrict__ G,
    const float* __restrict__ w1, const float* __restrict__ b1,
    const float* __restrict__ w2, const float* __restrict__ b2,
    float* __restrict__ out, int B) {
  const int gid = blockIdx.x * blockDim.x + threadIdx.x;
  const int grp = gid >> 4;  // 16-lane group, 4 interleaved elements
  const int gl = threadIdx.x & 15;
  const int b0 = grp * 4;
  if (b0 >= B) return;
  // Clamp tail reads (duplicate element); stores are guarded below.
  const float* xb[4];
#pragma unroll
  for (int e = 0; e < 4; ++e) {
    int be = b0 + e;
    if (be >= B) be = B - 1;
    xb[e] = x + be * 8;
  }

  v2f fx[4], fy[4], fz[4];
  run_rx(xb, G, gl, fx);
  run_ry(xb, G + 128, gl, fy);
  run_rz(xb, G + 256, gl, fz);

  // MLP head, lane-parallel over 12 hidden units; weights shared by all elems
  const int j = (gl < 12) ? gl : 0;
  const float* w1r = w1 + j * 6;
  const float w10 = w1r[0], w11 = w1r[1], w12 = w1r[2];
  const float w13 = w1r[3], w14 = w1r[4], w15 = w1r[5];
  const float b1v = b1[j], w2v = w2[j], b2v = b2[0];
  float t[4];
#pragma unroll
  for (int e = 0; e < 4; ++e) {
    const float a = b1v + w10 * fx[e].x + w11 * fx[e].y + w12 * fy[e].x +
                    w13 * fy[e].y + w14 * fz[e].x + w15 * fz[e].y;
    const float ev = __expf(2.f * a);
    const float th = 1.f - 2.f * __builtin_amdgcn_rcpf(ev + 1.f);
    t[e] = (gl < 12) ? w2v * th : 0.f;
  }
#pragma unroll
  for (int e = 0; e < 4; ++e) t[e] += swz1<1>(t[e]);
#pragma unroll
  for (int e = 0; e < 4; ++e) t[e] += swz1<2>(t[e]);
#pragma unroll
  for (int e = 0; e < 4; ++e) t[e] += swz1<4>(t[e]);
#pragma unroll
  for (int e = 0; e < 4; ++e) t[e] += swz1<8>(t[e]);
  if (gl == 0) {
#pragma unroll
    for (int e = 0; e < 4; ++e) {
      if (b0 + e < B) {
        out[b0 + e] = __builtin_amdgcn_rcpf(1.f + __expf(-(t[e] + b2v)));
      }
    }
  }
}

extern "C" void kernel_launch(void* const* d_in, const int* in_sizes, int n_in,
                              void* d_out, int out_size, void* d_ws,
                              size_t ws_size, hipStream_t stream) {
  const float* x = (const float*)d_in[0];
  const float* crx = (const float*)d_in[1];
  const float* u3x = (const float*)d_in[2];
  const float* cry = (const float*)d_in[3];
  const float* u3y = (const float*)d_in[4];
  const float* crz = (const float*)d_in[5];
  const float* u3z = (const float*)d_in[6];
  const float* w1 = (const float*)d_in[7];
  const float* b1 = (const float*)d_in[8];
  const float* w2 = (const float*)d_in[9];
  const float* b2 = (const float*)d_in[10];
  float* out = (float*)d_out;
  float* G = (float*)d_ws;  // 384 floats
  const int B = in_sizes[0] / 8;

  hipLaunchKernelGGL(qcnn_prep, dim3(1), dim3(64), 0, stream, crx, u3x, cry,
                     u3y, crz, u3z, G);
  const int ngroups = (B + 3) / 4;  // 4 elements per 16-lane group
  const int threads = 256;
  const int blocks = (ngroups * 16 + threads - 1) / threads;
  hipLaunchKernelGGL(qcnn_main, dim3(blocks), dim3(threads), 0, stream, x, G,
                     w1, b1, w2, b2, out, B);
}

// Round 4
// 113.573 us; speedup vs baseline: 1.0167x; 1.0167x over previous
//
#include <hip/hip_runtime.h>
#include <math.h>

// ---------------------------------------------------------------------------
// QCNN_Diff R13: I-fetch isolation via SEPARATE KERNEL LAUNCHES per branch.
// Model (fits all R8-R12 data): 32KB L1I is shared per 4-CU group; the fused
// kernel's ~46KB straight-line body thrashes it, so time ~ waves x code bytes
// (R10 more-waves null, R11 block-grouping null, R12 4-elem flat: bytes
// invariant). R8 (~24KB, fit) ran latency-bound at 44% VALUBusy.
// Fix: qcnn_rx / qcnn_ry / qcnn_rz as separate __global__ kernels launched
// sequentially -> device-wide only ~15KB of live code per launch, I$-resident.
// Branch math = validated R9 2-elem helpers, byte-identical (absmax 0.0).
// MLP head = validated qcnn_mlp from R10/R11 (absmax 0.0).
// Fused R9 kernel kept as fallback when ws is too small for feats.
// slot bits: q3->S0 q7->S1 q5->S2 q1->S3; lane bits: q0->L0 q2->L1 q4->L2 q6->L3
// ---------------------------------------------------------------------------

typedef float v2f __attribute__((ext_vector_type(2)));

__device__ __forceinline__ v2f mk2(float a, float b) { v2f r; r.x = a; r.y = b; return r; }
__device__ __forceinline__ v2f ld2(const float* __restrict__ p) { return *(const v2f*)p; }

// ---- VOP3P primitives, VGPR x VGPR -----------------------------------------
__device__ __forceinline__ v2f pk_mul_s(v2f a, v2f b) { v2f d;
  asm("v_pk_mul_f32 %0, %1, %2 op_sel:[0,0] op_sel_hi:[0,1]" : "=v"(d) : "v"(a), "v"(b)); return d; }
__device__ __forceinline__ v2f pk_fma_irot(v2f a, v2f b, v2f c) { v2f d;
  asm("v_pk_fma_f32 %0, %1, %2, %3 op_sel:[1,1,0] op_sel_hi:[1,0,1] neg_lo:[0,1,0]" : "=v"(d) : "v"(a), "v"(b), "v"(c)); return d; }
__device__ __forceinline__ v2f cmul(v2f a, v2f b) { return pk_fma_irot(a, b, pk_mul_s(a, b)); }
__device__ __forceinline__ v2f pk_mul_swap(v2f a, v2f b) { v2f d;
  asm("v_pk_mul_f32 %0, %1, %2 op_sel:[1,0] op_sel_hi:[0,1]" : "=v"(d) : "v"(a), "v"(b)); return d; }

// ---- VOP3P primitives, SGPR (wave-uniform) first operand -------------------
__device__ __forceinline__ v2f pk_mul_sM(v2f M, v2f b) { v2f d;
  asm("v_pk_mul_f32 %0, %1, %2 op_sel:[0,0] op_sel_hi:[0,1]" : "=v"(d) : "s"(M), "v"(b)); return d; }
__device__ __forceinline__ v2f pk_fma_sloM(v2f M, v2f b, v2f c) { v2f d;
  asm("v_pk_fma_f32 %0, %1, %2, %3 op_sel:[0,0,0] op_sel_hi:[0,1,1]" : "=v"(d) : "s"(M), "v"(b), "v"(c)); return d; }
__device__ __forceinline__ v2f pk_fma_shiM(v2f M, v2f b, v2f c) { v2f d;
  asm("v_pk_fma_f32 %0, %1, %2, %3 op_sel:[1,0,0] op_sel_hi:[1,1,1]" : "=v"(d) : "s"(M), "v"(b), "v"(c)); return d; }
__device__ __forceinline__ v2f pk_fma_shi_negM(v2f M, v2f b, v2f c) { v2f d;
  asm("v_pk_fma_f32 %0, %1, %2, %3 op_sel:[1,0,0] op_sel_hi:[1,1,1] neg_lo:[1,0,0] neg_hi:[1,0,0]" : "=v"(d) : "s"(M), "v"(b), "v"(c)); return d; }
__device__ __forceinline__ v2f pk_fma_rotM(v2f M, v2f b, v2f c) { v2f d;
  asm("v_pk_fma_f32 %0, %1, %2, %3 op_sel:[1,1,0] op_sel_hi:[1,0,1] neg_hi:[0,1,0]" : "=v"(d) : "s"(M), "v"(b), "v"(c)); return d; }
__device__ __forceinline__ v2f pk_fma_irotM(v2f M, v2f b, v2f c) { v2f d;
  asm("v_pk_fma_f32 %0, %1, %2, %3 op_sel:[1,1,0] op_sel_hi:[1,0,1] neg_lo:[0,1,0]" : "=v"(d) : "s"(M), "v"(b), "v"(c)); return d; }

template <int MASK>
__device__ __forceinline__ float swz1(float v) {
  constexpr int pat = (MASK << 10) | 0x1F;  // xor-mode
  return __int_as_float(__builtin_amdgcn_ds_swizzle(__float_as_int(v), pat));
}
template <int MASK>
__device__ __forceinline__ v2f swz2(v2f v) {
  v2f r; r.x = swz1<MASK>(v.x); r.y = swz1<MASK>(v.y); return r;
}

// ---- u3 row: ua*a + ub*b, matrices from SGPRs ------------------------------
template <bool A_REAL>
__device__ __forceinline__ v2f u3row_s(v2f ua, v2f ub, v2f a, v2f b) {
  v2f t = pk_mul_sM(ua, a);
  if constexpr (!A_REAL) t = pk_fma_irotM(ua, a, t);
  t = pk_fma_sloM(ub, b, t);
  return pk_fma_irotM(ub, b, t);
}

// All gate helpers operate on w[32] = two interleaved elements; slot-pair
// bits are the low 4 index bits, element = bit 4, so i|(1<<SB) stays in-element.
template <int SB>
__device__ __forceinline__ void u3_apply(v2f w[32], const float* __restrict__ p) {
  const v2f M0 = ld2(p), M1 = ld2(p + 2), M2 = ld2(p + 4), M3 = ld2(p + 6);
#pragma unroll
  for (int i = 0; i < 32; ++i) {
    if (i & (1 << SB)) continue;
    const int i1 = i | (1 << SB);
    const v2f a = w[i], b = w[i1];
    w[i] = u3row_s<true>(M0, M1, a, b);
    w[i1] = u3row_s<false>(M3, M2, b, a);
  }
}

template <int SB, int CB, bool M00R>
__device__ __forceinline__ void u3_sel(v2f w[32], const float* __restrict__ pM,
                                       const float* __restrict__ pN) {
  const v2f M0 = ld2(pM), M1 = ld2(pM + 2), M2 = ld2(pM + 4), M3 = ld2(pM + 6);
  const v2f N0 = ld2(pN), N1 = ld2(pN + 2), N2 = ld2(pN + 4), N3 = ld2(pN + 6);
#pragma unroll
  for (int i = 0; i < 32; ++i) {
    if (i & (1 << SB)) continue;
    const int i1 = i | (1 << SB);
    const v2f a = w[i], b = w[i1];
    if ((i >> CB) & 1) {
      w[i] = u3row_s<false>(N0, N1, a, b);
      w[i1] = u3row_s<false>(N3, N2, b, a);
    } else {
      w[i] = u3row_s<M00R>(M0, M1, a, b);
      w[i1] = u3row_s<false>(M3, M2, b, a);
    }
  }
}

template <int SB, int LB>
__device__ __forceinline__ void crx_Sc_Lt(v2f w[32], v2f cs) {
#pragma unroll
  for (int i = 0; i < 32; ++i) {
    if (!(i & (1 << SB))) continue;
    const v2f p = swz2<(1 << LB)>(w[i]);
    w[i] = pk_fma_rotM(cs, p, pk_mul_sM(cs, w[i]));
  }
}

template <int SB, int LB>
__device__ __forceinline__ void cr_ry_r(float w[32], v2f cs, int gl) {
  const bool tb = (gl >> LB) & 1;
  const float Ky = tb ? cs.y : -cs.y;
#pragma unroll
  for (int i = 0; i < 32; ++i) {
    if (!(i & (1 << SB))) continue;
    const float p = swz1<(1 << LB)>(w[i]);
    w[i] = __builtin_fmaf(Ky, p, cs.x * w[i]);
  }
}

template <int KIND, int SBc, int SBt>
__device__ __forceinline__ void cr_Sc_St(v2f w[32], v2f cs) {
#pragma unroll
  for (int i = 0; i < 32; ++i) {
    if (!(i & (1 << SBc))) continue;
    if constexpr (KIND == 2) {
      const v2f t = pk_mul_sM(cs, w[i]);
      w[i] = (i & (1 << SBt)) ? pk_fma_irotM(cs, w[i], t)
                              : pk_fma_rotM(cs, w[i], t);
    } else {
      if (i & (1 << SBt)) continue;
      const int i1 = i | (1 << SBt);
      const v2f a = w[i], b = w[i1];
      if constexpr (KIND == 0) {
        w[i] = pk_fma_rotM(cs, b, pk_mul_sM(cs, a));
        w[i1] = pk_fma_rotM(cs, a, pk_mul_sM(cs, b));
      } else {
        w[i] = pk_fma_shi_negM(cs, b, pk_mul_sM(cs, a));
        w[i1] = pk_fma_shiM(cs, a, pk_mul_sM(cs, b));
      }
    }
  }
}

template <int SB>
__device__ __forceinline__ void u3_lift(v2f w[32], const float wr[32],
                                        const float* __restrict__ p) {
  const v2f M0 = ld2(p), M1 = ld2(p + 2), M2 = ld2(p + 4), M3 = ld2(p + 6);
#pragma unroll
  for (int i = 0; i < 32; ++i) {
    if (i & (1 << SB)) continue;
    const int i1 = i | (1 << SB);
    const float a = wr[i], b = wr[i1];
    w[i] = mk2(__builtin_fmaf(a, M0.x, b * M1.x), b * M1.y);
    w[i1] = mk2(__builtin_fmaf(a, M2.x, b * M3.x),
                __builtin_fmaf(a, M2.y, b * M3.y));
  }
}

__device__ __forceinline__ void measure2(v2f w[32], const float* __restrict__ q,
                                         v2f res[2]) {
  const v2f qa = ld2(q);      // (alpha, beta)
  const v2f qg = ld2(q + 2);  // (gr, gi)
  float z3[2], z7[2];
#pragma unroll
  for (int e = 0; e < 2; ++e) {
    float z3a = 0.f, z3b = 0.f, z7p = 0.f, z7m = 0.f;
#pragma unroll
    for (int s0 = 0; s0 < 16; s0 += 2) {
      const v2f a = w[e * 16 + s0], b = w[e * 16 + s0 + 1];
      const v2f t1 = a * b, t2 = pk_mul_swap(a, b), t3 = a * a, t4 = b * b;
      const float r = t1.x + t1.y;
      const float m = t2.x - t2.y;
      const float na = t3.x + t3.y;
      const float nb = t4.x + t4.y;
      z3a = __builtin_fmaf(qa.x, na, z3a);
      z3b = __builtin_fmaf(qa.y, nb, z3b);
      z3a = __builtin_fmaf(qg.x, r, z3a);
      z3b = __builtin_fmaf(-qg.y, m, z3b);
      const float nn = na + nb;
      if (s0 & 2) z7m += nn; else z7p += nn;
    }
    z3[e] = z3a + z3b;
    z7[e] = z7p - z7m;
  }
  z3[0] += swz1<1>(z3[0]); z3[1] += swz1<1>(z3[1]); z7[0] += swz1<1>(z7[0]); z7[1] += swz1<1>(z7[1]);
  z3[0] += swz1<2>(z3[0]); z3[1] += swz1<2>(z3[1]); z7[0] += swz1<2>(z7[0]); z7[1] += swz1<2>(z7[1]);
  z3[0] += swz1<4>(z3[0]); z3[1] += swz1<4>(z3[1]); z7[0] += swz1<4>(z7[0]); z7[1] += swz1<4>(z7[1]);
  z3[0] += swz1<8>(z3[0]); z3[1] += swz1<8>(z3[1]); z7[0] += swz1<8>(z7[0]); z7[1] += swz1<8>(z7[1]);
  res[0] = mk2(z3[0], z7[0]);
  res[1] = mk2(z3[1], z7[1]);
}

template <int KIND>
__device__ __forceinline__ void tail_common(v2f w[32], const float* __restrict__ Gb,
                                            v2f res[2]) {
  u3_sel<0, 3, true>(w, Gb + 72, Gb + 80);    // U3first(3) / R13.U3first(3)
  u3_apply<2>(w, Gb + 88);                    // U3(5)
  u3_sel<1, 2, false>(w, Gb + 96, Gb + 104);  // Uf7.U7 / Uf7.R57.U7
  cr_Sc_St<KIND, 0, 2>(w, ld2(Gb + 56));      // CR(3,5)
  measure2(w, Gb + 112, res);                 // folds U3final(3)
}

__device__ __forceinline__ void load_sincos(const float* __restrict__ xb,
                                            float sn[8], float cn[8]) {
  const float4 xlo = ((const float4*)xb)[0];
  const float4 xhi = ((const float4*)xb)[1];
  const float xq[8] = {xlo.x, xlo.y, xlo.z, xlo.w, xhi.x, xhi.y, xhi.z, xhi.w};
#pragma unroll
  for (int q = 0; q < 8; ++q) __sincosf(0.5f * xq[q], &sn[q], &cn[q]);
}

// ============================ branch heads ==================================
__device__ __forceinline__ void run_rx(const float* __restrict__ xb0,
                                       const float* __restrict__ xb1,
                                       const float* __restrict__ Gb, int gl,
                                       v2f res[2]) {
  const bool l0 = gl & 1, l1 = (gl >> 1) & 1, l2 = (gl >> 2) & 1, l3 = (gl >> 3) & 1;
  v2f w[32];
#pragma unroll
  for (int e = 0; e < 2; ++e) {
    float sn[8], cn[8];
    load_sincos(e ? xb1 : xb0, sn, cn);
    v2f pa[4], pb[4];
#pragma unroll
    for (int pr = 0; pr < 4; ++pr) {
      const bool lh = (pr == 0) ? l0 : (pr == 1) ? l1 : (pr == 2) ? l2 : l3;
      const float c = Gb[pr * 8], s = Gb[pr * 8 + 1];
      const float uc = lh ? sn[2 * pr] : cn[2 * pr];
      const float b0 = uc * cn[2 * pr + 1], b1 = uc * sn[2 * pr + 1];
      const float Kx = lh ? c : 1.f;
      const float Kyn = lh ? -s : 0.f;
      pa[pr] = mk2(Kx * b0, Kyn * b1);
      pb[pr] = mk2(Kx * b1, Kyn * b0);
    }
    v2f A[4] = {cmul(pa[0], pa[2]), cmul(pa[0], pb[2]), cmul(pb[0], pa[2]), cmul(pb[0], pb[2])};
    v2f Bv[4] = {cmul(pa[3], pa[1]), cmul(pa[3], pb[1]), cmul(pb[3], pa[1]), cmul(pb[3], pb[1])};
#pragma unroll
    for (int s = 0; s < 16; ++s) w[e * 16 + s] = cmul(A[s >> 2], Bv[s & 3]);
  }
  crx_Sc_Lt<3, 1>(w, ld2(Gb + 32));  // (1,2)
  crx_Sc_Lt<0, 2>(w, ld2(Gb + 40));  // (3,4)
  crx_Sc_Lt<2, 3>(w, ld2(Gb + 48));  // (5,6)
  u3_apply<3>(w, Gb + 64);           // U3(1)
  tail_common<0>(w, Gb, res);
}

__device__ __forceinline__ void run_ry(const float* __restrict__ xb0,
                                       const float* __restrict__ xb1,
                                       const float* __restrict__ Gb, int gl,
                                       v2f res[2]) {
  const bool l0 = gl & 1, l1 = (gl >> 1) & 1, l2 = (gl >> 2) & 1, l3 = (gl >> 3) & 1;
  float wr[32];
#pragma unroll
  for (int e = 0; e < 2; ++e) {
    float sn[8], cn[8];
    load_sincos(e ? xb1 : xb0, sn, cn);
    float pa[4], pb[4];
#pragma unroll
    for (int pr = 0; pr < 4; ++pr) {
      const bool lh = (pr == 0) ? l0 : (pr == 1) ? l1 : (pr == 2) ? l2 : l3;
      const float c = Gb[pr * 8], s = Gb[pr * 8 + 1];
      const float uc = lh ? sn[2 * pr] : cn[2 * pr];
      const float b0 = uc * cn[2 * pr + 1], b1 = uc * sn[2 * pr + 1];
      const float Kx = lh ? c : 1.f;
      const float Ky = lh ? s : 0.f;
      pa[pr] = Kx * b0 - Ky * b1;
      pb[pr] = Ky * b0 + Kx * b1;
    }
    const float A[4] = {pa[0] * pa[2], pa[0] * pb[2], pb[0] * pa[2], pb[0] * pb[2]};
    const float Bv[4] = {pa[3] * pa[1], pa[3] * pb[1], pb[3] * pa[1], pb[3] * pb[1]};
#pragma unroll
    for (int s = 0; s < 16; ++s) wr[e * 16 + s] = A[s >> 2] * Bv[s & 3];
  }
  cr_ry_r<3, 1>(wr, ld2(Gb + 32), gl);
  cr_ry_r<0, 2>(wr, ld2(Gb + 40), gl);
  cr_ry_r<2, 3>(wr, ld2(Gb + 48), gl);
  v2f w[32];
  u3_lift<3>(w, wr, Gb + 64);        // U3(1), real input
  tail_common<1>(w, Gb, res);
}

__device__ __forceinline__ void run_rz(const float* __restrict__ xb0,
                                       const float* __restrict__ xb1,
                                       const float* __restrict__ Gb, int gl,
                                       v2f res[2]) {
  const bool l0 = gl & 1, l1 = (gl >> 1) & 1, l2 = (gl >> 2) & 1, l3 = (gl >> 3) & 1;
  // shared phase coefficients (element-independent)
  const float t0 = Gb[2], h0 = Gb[3];
  const float t1 = Gb[10], h1 = Gb[11];
  const float t2 = Gb[18], h2 = Gb[19];
  const float t3 = Gb[26], h3 = Gb[27];
  const float h4 = Gb[35], h5 = Gb[43], h6 = Gb[51];
  const float kk0 = (l1 ? t1 : 0.f) + (l2 ? h5 : -h5);
  const float kk1 = (l3 ? t3 : 0.f);
  const float kk2 = (l2 ? t2 : 0.f) + (l3 ? h6 : -h6);
  const float kk3 = (l0 ? t0 : 0.f) + (l1 ? h4 : -h4);
  const float aa = -((l0 ? h0 : 0.f) + (l1 ? h1 : 0.f) + (l2 ? h2 : 0.f) + (l3 ? h3 : 0.f));
  // per-element real envelopes
  float v01[2][4], v23[2][4];
#pragma unroll
  for (int e = 0; e < 2; ++e) {
    float sn[8], cn[8];
    load_sincos(e ? xb1 : xb0, sn, cn);
    const float u0 = l0 ? sn[0] : cn[0];
    const float u2 = l1 ? sn[2] : cn[2];
    const float u4 = l2 ? sn[4] : cn[4];
    const float u6 = l3 ? sn[6] : cn[6];
    const float P = (u0 * u2) * (u4 * u6);
    v01[e][0] = P * (cn[3] * cn[7]); v01[e][1] = P * (sn[3] * cn[7]);
    v01[e][2] = P * (cn[3] * sn[7]); v01[e][3] = P * (sn[3] * sn[7]);
    v23[e][0] = cn[5] * cn[1]; v23[e][1] = sn[5] * cn[1];
    v23[e][2] = cn[5] * sn[1]; v23[e][3] = sn[5] * sn[1];
  }
  v2f w[32];
#pragma unroll
  for (int s = 0; s < 16; ++s) {
    float phv = aa;
    if (s & 1) phv += kk0;
    if (s & 2) phv += kk1;
    if (s & 4) phv += kk2;
    if (s & 8) phv += kk3;
    float sp, cp;
    __sincosf(phv, &sp, &cp);  // shared by both elements
    const float e0 = v01[0][s & 3] * v23[0][s >> 2];
    const float e1 = v01[1][s & 3] * v23[1][s >> 2];
    w[s] = mk2(e0 * cp, e0 * sp);
    w[16 + s] = mk2(e1 * cp, e1 * sp);
  }
  u3_apply<3>(w, Gb + 64);           // U3(1)
  tail_common<2>(w, Gb, res);
}

// ============================ prep ==========================================
struct c2 { float r, i; };
__device__ __forceinline__ c2 cmulh(c2 a, c2 b) { return {a.r * b.r - a.i * b.i, a.r * b.i + a.i * b.r}; }
__device__ __forceinline__ c2 cmulc(c2 a, c2 b) { return {a.r * b.r + a.i * b.i, a.i * b.r - a.r * b.i}; }
__device__ __forceinline__ c2 caddh(c2 a, c2 b) { return {a.r + b.r, a.i + b.i}; }
__device__ void mat2mul(const c2 A[4], const c2 B[4], c2 C[4]) {
  C[0] = caddh(cmulh(A[0], B[0]), cmulh(A[1], B[2]));
  C[1] = caddh(cmulh(A[0], B[1]), cmulh(A[1], B[3]));
  C[2] = caddh(cmulh(A[2], B[0]), cmulh(A[3], B[2]));
  C[3] = caddh(cmulh(A[2], B[1]), cmulh(A[3], B[3]));
}
__device__ void u3m(const float* p, c2 M[4]) {
  float st, ct, sp, cp, sl, cl;
  sincosf(0.5f * p[0], &st, &ct);
  sincosf(p[1], &sp, &cp);
  sincosf(p[2], &sl, &cl);
  M[0] = {ct, 0.f};
  M[1] = {-cl * st, -sl * st};
  M[2] = {cp * st, sp * st};
  M[3] = {(cp * cl - sp * sl) * ct, (sp * cl + cp * sl) * ct};
}
__device__ void rmat(int kind, float th, c2 R[4]) {
  float s, c;
  sincosf(0.5f * th, &s, &c);
  if (kind == 0) { R[0] = {c, 0.f}; R[1] = {0.f, -s}; R[2] = {0.f, -s}; R[3] = {c, 0.f}; }
  else if (kind == 1) { R[0] = {c, 0.f}; R[1] = {-s, 0.f}; R[2] = {s, 0.f}; R[3] = {c, 0.f}; }
  else { R[0] = {c, -s}; R[1] = {0.f, 0.f}; R[2] = {0.f, 0.f}; R[3] = {c, s}; }
}
__device__ void storeM(float* dst, const c2 M[4]) {
#pragma unroll
  for (int j = 0; j < 4; ++j) { dst[2 * j] = M[j].r; dst[2 * j + 1] = M[j].i; }
}

__global__ void qcnn_prep(const float* __restrict__ crx, const float* __restrict__ u3x,
                          const float* __restrict__ cry, const float* __restrict__ u3y,
                          const float* __restrict__ crz, const float* __restrict__ u3z,
                          float* __restrict__ G) {
  const int br = threadIdx.x;
  if (br >= 3) return;
  const float* crp = (br == 0) ? crx : (br == 1) ? cry : crz;
  const float* u3p = (br == 0) ? u3x : (br == 1) ? u3y : u3z;
  float* Gb = G + br * 128;

  const int crIdx[8] = {0, 1, 2, 3, 4, 5, 6, 9};
#pragma unroll
  for (int i = 0; i < 8; ++i) {
    const float th = crp[crIdx[i]];
    float s, c;
    sincosf(0.5f * th, &s, &c);
    Gb[i * 8] = c;
    Gb[i * 8 + 1] = s;
    Gb[i * 8 + 2] = th;
    Gb[i * 8 + 3] = 0.5f * th;
  }
  c2 U1v[4], U3v[4], U5v[4], U7a[4], U7b[4], U3f[4], R[4], T[4], T2[4];
  u3m(u3p + 0, U1v);
  u3m(u3p + 3, U3v);
  u3m(u3p + 6, U5v);
  u3m(u3p + 9, U7a);
  u3m(u3p + 12, U3f);
  u3m(u3p + 15, U7b);
  storeM(Gb + 64, U1v);
  storeM(Gb + 72, U3v);
  rmat(br, crp[7], R);
  mat2mul(R, U3v, T);
  storeM(Gb + 80, T);
  storeM(Gb + 88, U5v);
  mat2mul(U7b, U7a, T);
  storeM(Gb + 96, T);
  rmat(br, crp[8], R);
  mat2mul(R, U7a, T);
  mat2mul(U7b, T, T2);
  storeM(Gb + 104, T2);
  const float n00 = U3f[0].r * U3f[0].r + U3f[0].i * U3f[0].i;
  const float n01 = U3f[1].r * U3f[1].r + U3f[1].i * U3f[1].i;
  const float n10 = U3f[2].r * U3f[2].r + U3f[2].i * U3f[2].i;
  const float n11 = U3f[3].r * U3f[3].r + U3f[3].i * U3f[3].i;
  const c2 g01 = cmulc(U3f[0], U3f[1]);
  const c2 g23 = cmulc(U3f[2], U3f[3]);
  Gb[112] = n00 - n10;
  Gb[113] = n01 - n11;
  Gb[114] = 2.f * (g01.r - g23.r);
  Gb[115] = 2.f * (g01.i - g23.i);
}

// ===================== per-branch kernels (I$-resident) =====================
// Launched sequentially; at any instant the device executes only ONE ~15KB
// code body, which fits the shared L1I. feats layout [B][6].
__global__ __launch_bounds__(256) void qcnn_rx(
    const float* __restrict__ x, const float* __restrict__ G,
    float* __restrict__ feats, int B) {
  const int gid = blockIdx.x * blockDim.x + threadIdx.x;
  const int grp = gid >> 4;
  const int gl = threadIdx.x & 15;
  const int b0 = grp * 2;
  if (b0 >= B) return;
  v2f res[2];
  run_rx(x + b0 * 8, x + (b0 + 1) * 8, G, gl, res);
  if (gl == 0) {
    *(v2f*)(feats + b0 * 6 + 0) = res[0];
    *(v2f*)(feats + (b0 + 1) * 6 + 0) = res[1];
  }
}

__global__ __launch_bounds__(256) void qcnn_ry(
    const float* __restrict__ x, const float* __restrict__ G,
    float* __restrict__ feats, int B) {
  const int gid = blockIdx.x * blockDim.x + threadIdx.x;
  const int grp = gid >> 4;
  const int gl = threadIdx.x & 15;
  const int b0 = grp * 2;
  if (b0 >= B) return;
  v2f res[2];
  run_ry(x + b0 * 8, x + (b0 + 1) * 8, G + 128, gl, res);
  if (gl == 0) {
    *(v2f*)(feats + b0 * 6 + 2) = res[0];
    *(v2f*)(feats + (b0 + 1) * 6 + 2) = res[1];
  }
}

__global__ __launch_bounds__(256) void qcnn_rz(
    const float* __restrict__ x, const float* __restrict__ G,
    float* __restrict__ feats, int B) {
  const int gid = blockIdx.x * blockDim.x + threadIdx.x;
  const int grp = gid >> 4;
  const int gl = threadIdx.x & 15;
  const int b0 = grp * 2;
  if (b0 >= B) return;
  v2f res[2];
  run_rz(x + b0 * 8, x + (b0 + 1) * 8, G + 256, gl, res);
  if (gl == 0) {
    *(v2f*)(feats + b0 * 6 + 4) = res[0];
    *(v2f*)(feats + (b0 + 1) * 6 + 4) = res[1];
  }
}

__global__ __launch_bounds__(256) void qcnn_mlp(
    const float* __restrict__ feats, const float* __restrict__ w1,
    const float* __restrict__ b1, const float* __restrict__ w2,
    const float* __restrict__ b2, float* __restrict__ out, int B) {
  const int b = blockIdx.x * blockDim.x + threadIdx.x;
  if (b >= B) return;
  const float* f = feats + b * 6;
  const v2f f01 = ld2(f), f23 = ld2(f + 2), f45 = ld2(f + 4);
  const float b2v = b2[0];
  float acc = b2v;
#pragma unroll
  for (int j = 0; j < 12; ++j) {
    const float* wr = w1 + j * 6;
    float a = b1[j];
    a = __builtin_fmaf(wr[0], f01.x, a);
    a = __builtin_fmaf(wr[1], f01.y, a);
    a = __builtin_fmaf(wr[2], f23.x, a);
    a = __builtin_fmaf(wr[3], f23.y, a);
    a = __builtin_fmaf(wr[4], f45.x, a);
    a = __builtin_fmaf(wr[5], f45.y, a);
    const float e = __expf(2.f * a);
    const float th = 1.f - 2.f * __builtin_amdgcn_rcpf(e + 1.f);
    acc = __builtin_fmaf(w2[j], th, acc);
  }
  out[b] = __builtin_amdgcn_rcpf(1.f + __expf(-acc));
}

// ============================ fused fallback ================================
__global__ __launch_bounds__(256) void qcnn_main(
    const float* __restrict__ x, const float* __restrict__ G,
    const float* __restrict__ w1, const float* __restrict__ b1,
    const float* __restrict__ w2, const float* __restrict__ b2,
    float* __restrict__ out, int B) {
  const int gid = blockIdx.x * blockDim.x + threadIdx.x;
  const int grp = gid >> 4;  // 16-lane group, 2 interleaved elements
  const int gl = threadIdx.x & 15;
  const int b0 = grp * 2;
  if (b0 >= B) return;  // B is even; b0+1 < B whenever b0 < B
  const float* xb0 = x + b0 * 8;
  const float* xb1 = x + (b0 + 1) * 8;

  v2f fx[2], fy[2], fz[2];
  run_rx(xb0, xb1, G, gl, fx);
  run_ry(xb0, xb1, G + 128, gl, fy);
  run_rz(xb0, xb1, G + 256, gl, fz);

  const int j = (gl < 12) ? gl : 0;
  const float* w1r = w1 + j * 6;
  const float w10 = w1r[0], w11 = w1r[1], w12 = w1r[2];
  const float w13 = w1r[3], w14 = w1r[4], w15 = w1r[5];
  const float b1v = b1[j], w2v = w2[j], b2v = b2[0];
  float a0 = b1v + w10 * fx[0].x + w11 * fx[0].y + w12 * fy[0].x +
             w13 * fy[0].y + w14 * fz[0].x + w15 * fz[0].y;
  float a1 = b1v + w10 * fx[1].x + w11 * fx[1].y + w12 * fy[1].x +
             w13 * fy[1].y + w14 * fz[1].x + w15 * fz[1].y;
  const float e0 = __expf(2.f * a0), e1 = __expf(2.f * a1);
  const float th0 = 1.f - 2.f * __builtin_amdgcn_rcpf(e0 + 1.f);
  const float th1 = 1.f - 2.f * __builtin_amdgcn_rcpf(e1 + 1.f);
  float t0 = (gl < 12) ? w2v * th0 : 0.f;
  float t1 = (gl < 12) ? w2v * th1 : 0.f;
  t0 += swz1<1>(t0); t1 += swz1<1>(t1);
  t0 += swz1<2>(t0); t1 += swz1<2>(t1);
  t0 += swz1<4>(t0); t1 += swz1<4>(t1);
  t0 += swz1<8>(t0); t1 += swz1<8>(t1);
  const float r0 = __builtin_amdgcn_rcpf(1.f + __expf(-(t0 + b2v)));
  const float r1 = __builtin_amdgcn_rcpf(1.f + __expf(-(t1 + b2v)));
  if (gl == 0) {
    out[b0] = r0;
    out[b0 + 1] = r1;
  }
}

extern "C" void kernel_launch(void* const* d_in, const int* in_sizes, int n_in,
                              void* d_out, int out_size, void* d_ws,
                              size_t ws_size, hipStream_t stream) {
  const float* x = (const float*)d_in[0];
  const float* crx = (const float*)d_in[1];
  const float* u3x = (const float*)d_in[2];
  const float* cry = (const float*)d_in[3];
  const float* u3y = (const float*)d_in[4];
  const float* crz = (const float*)d_in[5];
  const float* u3z = (const float*)d_in[6];
  const float* w1 = (const float*)d_in[7];
  const float* b1 = (const float*)d_in[8];
  const float* w2 = (const float*)d_in[9];
  const float* b2 = (const float*)d_in[10];
  float* out = (float*)d_out;
  float* G = (float*)d_ws;  // 384 floats
  const int B = in_sizes[0] / 8;

  hipLaunchKernelGGL(qcnn_prep, dim3(1), dim3(64), 0, stream, crx, u3x, cry,
                     u3y, crz, u3z, G);

  const int ngroups = (B + 1) / 2;  // 2 elements per 16-lane group
  const int threads = 256;
  const int blocks = (ngroups * 16 + threads - 1) / threads;
  const size_t need = (size_t)(384 + (size_t)B * 6) * sizeof(float);

  if (ws_size >= need) {
    float* feats = G + 384;  // [B][6]
    hipLaunchKernelGGL(qcnn_rx, dim3(blocks), dim3(threads), 0, stream, x, G,
                       feats, B);
    hipLaunchKernelGGL(qcnn_ry, dim3(blocks), dim3(threads), 0, stream, x, G,
                       feats, B);
    hipLaunchKernelGGL(qcnn_rz, dim3(blocks), dim3(threads), 0, stream, x, G,
                       feats, B);
    const int mblocks = (B + threads - 1) / threads;
    hipLaunchKernelGGL(qcnn_mlp, dim3(mblocks), dim3(threads), 0, stream,
                       feats, w1, b1, w2, b2, out, B);
  } else {
    hipLaunchKernelGGL(qcnn_main, dim3(blocks), dim3(threads), 0, stream, x, G,
                       w1, b1, w2, b2, out, B);
  }
}

// Round 5
// 106.566 us; speedup vs baseline: 1.0835x; 1.0657x over previous
//
#include <hip/hip_runtime.h>
#include <math.h>

// ---------------------------------------------------------------------------
// QCNN_Diff R14: replace XOR-1/XOR-2 ds_swizzle with DPP quad_perm (pure VALU,
// no LDS pipe / lgkmcnt). Theory: after R10 (waves) / R11 (code mix) / R12
// (ILP) / R13 (I$ isolation) all nulled, the remaining stall source with the
// right magnitude is ds_swizzle latency (~40-120cy, m117) x ~200 ops/wave with
// shallow outstanding-buffer at VGPR=64 -> recurrent lgkmcnt waits. DPP covers
// XOR masks 1 (quad_perm [1,0,3,2]=0xB1) and 2 ([2,3,0,1]=0x4E): ~38% of all
// DS ops (rx CRX(1,2) 32, ry cr(3,1) 16, measure 8x3, mlp 2) become VALU movs.
// Everything else byte-identical to the validated R9 fused kernel (absmax 0.0,
// best measured total 106.7us). Single isolated change -> clean A/B.
// slot bits: q3->S0 q7->S1 q5->S2 q1->S3; lane bits: q0->L0 q2->L1 q4->L2 q6->L3
// ---------------------------------------------------------------------------

typedef float v2f __attribute__((ext_vector_type(2)));

__device__ __forceinline__ v2f mk2(float a, float b) { v2f r; r.x = a; r.y = b; return r; }
__device__ __forceinline__ v2f ld2(const float* __restrict__ p) { return *(const v2f*)p; }

// ---- VOP3P primitives, VGPR x VGPR -----------------------------------------
__device__ __forceinline__ v2f pk_mul_s(v2f a, v2f b) { v2f d;
  asm("v_pk_mul_f32 %0, %1, %2 op_sel:[0,0] op_sel_hi:[0,1]" : "=v"(d) : "v"(a), "v"(b)); return d; }
__device__ __forceinline__ v2f pk_fma_irot(v2f a, v2f b, v2f c) { v2f d;
  asm("v_pk_fma_f32 %0, %1, %2, %3 op_sel:[1,1,0] op_sel_hi:[1,0,1] neg_lo:[0,1,0]" : "=v"(d) : "v"(a), "v"(b), "v"(c)); return d; }
__device__ __forceinline__ v2f cmul(v2f a, v2f b) { return pk_fma_irot(a, b, pk_mul_s(a, b)); }
__device__ __forceinline__ v2f pk_mul_swap(v2f a, v2f b) { v2f d;
  asm("v_pk_mul_f32 %0, %1, %2 op_sel:[1,0] op_sel_hi:[0,1]" : "=v"(d) : "v"(a), "v"(b)); return d; }

// ---- VOP3P primitives, SGPR (wave-uniform) first operand -------------------
__device__ __forceinline__ v2f pk_mul_sM(v2f M, v2f b) { v2f d;
  asm("v_pk_mul_f32 %0, %1, %2 op_sel:[0,0] op_sel_hi:[0,1]" : "=v"(d) : "s"(M), "v"(b)); return d; }
__device__ __forceinline__ v2f pk_fma_sloM(v2f M, v2f b, v2f c) { v2f d;
  asm("v_pk_fma_f32 %0, %1, %2, %3 op_sel:[0,0,0] op_sel_hi:[0,1,1]" : "=v"(d) : "s"(M), "v"(b), "v"(c)); return d; }
__device__ __forceinline__ v2f pk_fma_shiM(v2f M, v2f b, v2f c) { v2f d;
  asm("v_pk_fma_f32 %0, %1, %2, %3 op_sel:[1,0,0] op_sel_hi:[1,1,1]" : "=v"(d) : "s"(M), "v"(b), "v"(c)); return d; }
__device__ __forceinline__ v2f pk_fma_shi_negM(v2f M, v2f b, v2f c) { v2f d;
  asm("v_pk_fma_f32 %0, %1, %2, %3 op_sel:[1,0,0] op_sel_hi:[1,1,1] neg_lo:[1,0,0] neg_hi:[1,0,0]" : "=v"(d) : "s"(M), "v"(b), "v"(c)); return d; }
__device__ __forceinline__ v2f pk_fma_rotM(v2f M, v2f b, v2f c) { v2f d;
  asm("v_pk_fma_f32 %0, %1, %2, %3 op_sel:[1,1,0] op_sel_hi:[1,0,1] neg_hi:[0,1,0]" : "=v"(d) : "s"(M), "v"(b), "v"(c)); return d; }
__device__ __forceinline__ v2f pk_fma_irotM(v2f M, v2f b, v2f c) { v2f d;
  asm("v_pk_fma_f32 %0, %1, %2, %3 op_sel:[1,1,0] op_sel_hi:[1,0,1] neg_lo:[0,1,0]" : "=v"(d) : "s"(M), "v"(b), "v"(c)); return d; }

// ---- cross-lane: DPP quad_perm for XOR 1/2 (VALU), ds_swizzle for 4/8 ------
template <int MASK>
__device__ __forceinline__ float swz1(float v) {
  if constexpr (MASK == 1) {
    // quad_perm [1,0,3,2] = 0xB1 : lane ^= 1, pure VALU, no lgkmcnt
    return __int_as_float(__builtin_amdgcn_update_dpp(
        0, __float_as_int(v), 0xB1, 0xF, 0xF, true));
  } else if constexpr (MASK == 2) {
    // quad_perm [2,3,0,1] = 0x4E : lane ^= 2
    return __int_as_float(__builtin_amdgcn_update_dpp(
        0, __float_as_int(v), 0x4E, 0xF, 0xF, true));
  } else {
    constexpr int pat = (MASK << 10) | 0x1F;  // xor-mode ds_swizzle
    return __int_as_float(__builtin_amdgcn_ds_swizzle(__float_as_int(v), pat));
  }
}
template <int MASK>
__device__ __forceinline__ v2f swz2(v2f v) {
  v2f r; r.x = swz1<MASK>(v.x); r.y = swz1<MASK>(v.y); return r;
}

// ---- u3 row: ua*a + ub*b, matrices from SGPRs ------------------------------
template <bool A_REAL>
__device__ __forceinline__ v2f u3row_s(v2f ua, v2f ub, v2f a, v2f b) {
  v2f t = pk_mul_sM(ua, a);
  if constexpr (!A_REAL) t = pk_fma_irotM(ua, a, t);
  t = pk_fma_sloM(ub, b, t);
  return pk_fma_irotM(ub, b, t);
}

// All gate helpers operate on w[32] = two interleaved elements; slot-pair
// bits are the low 4 index bits, element = bit 4, so i|(1<<SB) stays in-element.
template <int SB>
__device__ __forceinline__ void u3_apply(v2f w[32], const float* __restrict__ p) {
  const v2f M0 = ld2(p), M1 = ld2(p + 2), M2 = ld2(p + 4), M3 = ld2(p + 6);
#pragma unroll
  for (int i = 0; i < 32; ++i) {
    if (i & (1 << SB)) continue;
    const int i1 = i | (1 << SB);
    const v2f a = w[i], b = w[i1];
    w[i] = u3row_s<true>(M0, M1, a, b);
    w[i1] = u3row_s<false>(M3, M2, b, a);
  }
}

template <int SB, int CB, bool M00R>
__device__ __forceinline__ void u3_sel(v2f w[32], const float* __restrict__ pM,
                                       const float* __restrict__ pN) {
  const v2f M0 = ld2(pM), M1 = ld2(pM + 2), M2 = ld2(pM + 4), M3 = ld2(pM + 6);
  const v2f N0 = ld2(pN), N1 = ld2(pN + 2), N2 = ld2(pN + 4), N3 = ld2(pN + 6);
#pragma unroll
  for (int i = 0; i < 32; ++i) {
    if (i & (1 << SB)) continue;
    const int i1 = i | (1 << SB);
    const v2f a = w[i], b = w[i1];
    if ((i >> CB) & 1) {
      w[i] = u3row_s<false>(N0, N1, a, b);
      w[i1] = u3row_s<false>(N3, N2, b, a);
    } else {
      w[i] = u3row_s<M00R>(M0, M1, a, b);
      w[i1] = u3row_s<false>(M3, M2, b, a);
    }
  }
}

template <int SB, int LB>
__device__ __forceinline__ void crx_Sc_Lt(v2f w[32], v2f cs) {
#pragma unroll
  for (int i = 0; i < 32; ++i) {
    if (!(i & (1 << SB))) continue;
    const v2f p = swz2<(1 << LB)>(w[i]);
    w[i] = pk_fma_rotM(cs, p, pk_mul_sM(cs, w[i]));
  }
}

template <int SB, int LB>
__device__ __forceinline__ void cr_ry_r(float w[32], v2f cs, int gl) {
  const bool tb = (gl >> LB) & 1;
  const float Ky = tb ? cs.y : -cs.y;
#pragma unroll
  for (int i = 0; i < 32; ++i) {
    if (!(i & (1 << SB))) continue;
    const float p = swz1<(1 << LB)>(w[i]);
    w[i] = __builtin_fmaf(Ky, p, cs.x * w[i]);
  }
}

template <int KIND, int SBc, int SBt>
__device__ __forceinline__ void cr_Sc_St(v2f w[32], v2f cs) {
#pragma unroll
  for (int i = 0; i < 32; ++i) {
    if (!(i & (1 << SBc))) continue;
    if constexpr (KIND == 2) {
      const v2f t = pk_mul_sM(cs, w[i]);
      w[i] = (i & (1 << SBt)) ? pk_fma_irotM(cs, w[i], t)
                              : pk_fma_rotM(cs, w[i], t);
    } else {
      if (i & (1 << SBt)) continue;
      const int i1 = i | (1 << SBt);
      const v2f a = w[i], b = w[i1];
      if constexpr (KIND == 0) {
        w[i] = pk_fma_rotM(cs, b, pk_mul_sM(cs, a));
        w[i1] = pk_fma_rotM(cs, a, pk_mul_sM(cs, b));
      } else {
        w[i] = pk_fma_shi_negM(cs, b, pk_mul_sM(cs, a));
        w[i1] = pk_fma_shiM(cs, a, pk_mul_sM(cs, b));
      }
    }
  }
}

template <int SB>
__device__ __forceinline__ void u3_lift(v2f w[32], const float wr[32],
                                        const float* __restrict__ p) {
  const v2f M0 = ld2(p), M1 = ld2(p + 2), M2 = ld2(p + 4), M3 = ld2(p + 6);
#pragma unroll
  for (int i = 0; i < 32; ++i) {
    if (i & (1 << SB)) continue;
    const int i1 = i | (1 << SB);
    const float a = wr[i], b = wr[i1];
    w[i] = mk2(__builtin_fmaf(a, M0.x, b * M1.x), b * M1.y);
    w[i1] = mk2(__builtin_fmaf(a, M2.x, b * M3.x),
                __builtin_fmaf(a, M2.y, b * M3.y));
  }
}

__device__ __forceinline__ void measure2(v2f w[32], const float* __restrict__ q,
                                         v2f res[2]) {
  const v2f qa = ld2(q);      // (alpha, beta)
  const v2f qg = ld2(q + 2);  // (gr, gi)
  float z3[2], z7[2];
#pragma unroll
  for (int e = 0; e < 2; ++e) {
    float z3a = 0.f, z3b = 0.f, z7p = 0.f, z7m = 0.f;
#pragma unroll
    for (int s0 = 0; s0 < 16; s0 += 2) {
      const v2f a = w[e * 16 + s0], b = w[e * 16 + s0 + 1];
      const v2f t1 = a * b, t2 = pk_mul_swap(a, b), t3 = a * a, t4 = b * b;
      const float r = t1.x + t1.y;
      const float m = t2.x - t2.y;
      const float na = t3.x + t3.y;
      const float nb = t4.x + t4.y;
      z3a = __builtin_fmaf(qa.x, na, z3a);
      z3b = __builtin_fmaf(qa.y, nb, z3b);
      z3a = __builtin_fmaf(qg.x, r, z3a);
      z3b = __builtin_fmaf(-qg.y, m, z3b);
      const float nn = na + nb;
      if (s0 & 2) z7m += nn; else z7p += nn;
    }
    z3[e] = z3a + z3b;
    z7[e] = z7p - z7m;
  }
  z3[0] += swz1<1>(z3[0]); z3[1] += swz1<1>(z3[1]); z7[0] += swz1<1>(z7[0]); z7[1] += swz1<1>(z7[1]);
  z3[0] += swz1<2>(z3[0]); z3[1] += swz1<2>(z3[1]); z7[0] += swz1<2>(z7[0]); z7[1] += swz1<2>(z7[1]);
  z3[0] += swz1<4>(z3[0]); z3[1] += swz1<4>(z3[1]); z7[0] += swz1<4>(z7[0]); z7[1] += swz1<4>(z7[1]);
  z3[0] += swz1<8>(z3[0]); z3[1] += swz1<8>(z3[1]); z7[0] += swz1<8>(z7[0]); z7[1] += swz1<8>(z7[1]);
  res[0] = mk2(z3[0], z7[0]);
  res[1] = mk2(z3[1], z7[1]);
}

template <int KIND>
__device__ __forceinline__ void tail_common(v2f w[32], const float* __restrict__ Gb,
                                            v2f res[2]) {
  u3_sel<0, 3, true>(w, Gb + 72, Gb + 80);    // U3first(3) / R13.U3first(3)
  u3_apply<2>(w, Gb + 88);                    // U3(5)
  u3_sel<1, 2, false>(w, Gb + 96, Gb + 104);  // Uf7.U7 / Uf7.R57.U7
  cr_Sc_St<KIND, 0, 2>(w, ld2(Gb + 56));      // CR(3,5)
  measure2(w, Gb + 112, res);                 // folds U3final(3)
}

__device__ __forceinline__ void load_sincos(const float* __restrict__ xb,
                                            float sn[8], float cn[8]) {
  const float4 xlo = ((const float4*)xb)[0];
  const float4 xhi = ((const float4*)xb)[1];
  const float xq[8] = {xlo.x, xlo.y, xlo.z, xlo.w, xhi.x, xhi.y, xhi.z, xhi.w};
#pragma unroll
  for (int q = 0; q < 8; ++q) __sincosf(0.5f * xq[q], &sn[q], &cn[q]);
}

// ============================ branch heads ==================================
__device__ __forceinline__ void run_rx(const float* __restrict__ xb0,
                                       const float* __restrict__ xb1,
                                       const float* __restrict__ Gb, int gl,
                                       v2f res[2]) {
  const bool l0 = gl & 1, l1 = (gl >> 1) & 1, l2 = (gl >> 2) & 1, l3 = (gl >> 3) & 1;
  v2f w[32];
#pragma unroll
  for (int e = 0; e < 2; ++e) {
    float sn[8], cn[8];
    load_sincos(e ? xb1 : xb0, sn, cn);
    v2f pa[4], pb[4];
#pragma unroll
    for (int pr = 0; pr < 4; ++pr) {
      const bool lh = (pr == 0) ? l0 : (pr == 1) ? l1 : (pr == 2) ? l2 : l3;
      const float c = Gb[pr * 8], s = Gb[pr * 8 + 1];
      const float uc = lh ? sn[2 * pr] : cn[2 * pr];
      const float b0 = uc * cn[2 * pr + 1], b1 = uc * sn[2 * pr + 1];
      const float Kx = lh ? c : 1.f;
      const float Kyn = lh ? -s : 0.f;
      pa[pr] = mk2(Kx * b0, Kyn * b1);
      pb[pr] = mk2(Kx * b1, Kyn * b0);
    }
    v2f A[4] = {cmul(pa[0], pa[2]), cmul(pa[0], pb[2]), cmul(pb[0], pa[2]), cmul(pb[0], pb[2])};
    v2f Bv[4] = {cmul(pa[3], pa[1]), cmul(pa[3], pb[1]), cmul(pb[3], pa[1]), cmul(pb[3], pb[1])};
#pragma unroll
    for (int s = 0; s < 16; ++s) w[e * 16 + s] = cmul(A[s >> 2], Bv[s & 3]);
  }
  crx_Sc_Lt<3, 1>(w, ld2(Gb + 32));  // (1,2)  -> DPP path (mask 2)
  crx_Sc_Lt<0, 2>(w, ld2(Gb + 40));  // (3,4)  -> ds_swizzle (mask 4)
  crx_Sc_Lt<2, 3>(w, ld2(Gb + 48));  // (5,6)  -> ds_swizzle (mask 8)
  u3_apply<3>(w, Gb + 64);           // U3(1)
  tail_common<0>(w, Gb, res);
}

__device__ __forceinline__ void run_ry(const float* __restrict__ xb0,
                                       const float* __restrict__ xb1,
                                       const float* __restrict__ Gb, int gl,
                                       v2f res[2]) {
  const bool l0 = gl & 1, l1 = (gl >> 1) & 1, l2 = (gl >> 2) & 1, l3 = (gl >> 3) & 1;
  float wr[32];
#pragma unroll
  for (int e = 0; e < 2; ++e) {
    float sn[8], cn[8];
    load_sincos(e ? xb1 : xb0, sn, cn);
    float pa[4], pb[4];
#pragma unroll
    for (int pr = 0; pr < 4; ++pr) {
      const bool lh = (pr == 0) ? l0 : (pr == 1) ? l1 : (pr == 2) ? l2 : l3;
      const float c = Gb[pr * 8], s = Gb[pr * 8 + 1];
      const float uc = lh ? sn[2 * pr] : cn[2 * pr];
      const float b0 = uc * cn[2 * pr + 1], b1 = uc * sn[2 * pr + 1];
      const float Kx = lh ? c : 1.f;
      const float Ky = lh ? s : 0.f;
      pa[pr] = Kx * b0 - Ky * b1;
      pb[pr] = Ky * b0 + Kx * b1;
    }
    const float A[4] = {pa[0] * pa[2], pa[0] * pb[2], pb[0] * pa[2], pb[0] * pb[2]};
    const float Bv[4] = {pa[3] * pa[1], pa[3] * pb[1], pb[3] * pa[1], pb[3] * pb[1]};
#pragma unroll
    for (int s = 0; s < 16; ++s) wr[e * 16 + s] = A[s >> 2] * Bv[s & 3];
  }
  cr_ry_r<3, 1>(wr, ld2(Gb + 32), gl);  // mask 2 -> DPP
  cr_ry_r<0, 2>(wr, ld2(Gb + 40), gl);  // mask 4 -> DS
  cr_ry_r<2, 3>(wr, ld2(Gb + 48), gl);  // mask 8 -> DS
  v2f w[32];
  u3_lift<3>(w, wr, Gb + 64);        // U3(1), real input
  tail_common<1>(w, Gb, res);
}

__device__ __forceinline__ void run_rz(const float* __restrict__ xb0,
                                       const float* __restrict__ xb1,
                                       const float* __restrict__ Gb, int gl,
                                       v2f res[2]) {
  const bool l0 = gl & 1, l1 = (gl >> 1) & 1, l2 = (gl >> 2) & 1, l3 = (gl >> 3) & 1;
  // shared phase coefficients (element-independent)
  const float t0 = Gb[2], h0 = Gb[3];
  const float t1 = Gb[10], h1 = Gb[11];
  const float t2 = Gb[18], h2 = Gb[19];
  const float t3 = Gb[26], h3 = Gb[27];
  const float h4 = Gb[35], h5 = Gb[43], h6 = Gb[51];
  const float kk0 = (l1 ? t1 : 0.f) + (l2 ? h5 : -h5);
  const float kk1 = (l3 ? t3 : 0.f);
  const float kk2 = (l2 ? t2 : 0.f) + (l3 ? h6 : -h6);
  const float kk3 = (l0 ? t0 : 0.f) + (l1 ? h4 : -h4);
  const float aa = -((l0 ? h0 : 0.f) + (l1 ? h1 : 0.f) + (l2 ? h2 : 0.f) + (l3 ? h3 : 0.f));
  // per-element real envelopes
  float v01[2][4], v23[2][4];
#pragma unroll
  for (int e = 0; e < 2; ++e) {
    float sn[8], cn[8];
    load_sincos(e ? xb1 : xb0, sn, cn);
    const float u0 = l0 ? sn[0] : cn[0];
    const float u2 = l1 ? sn[2] : cn[2];
    const float u4 = l2 ? sn[4] : cn[4];
    const float u6 = l3 ? sn[6] : cn[6];
    const float P = (u0 * u2) * (u4 * u6);
    v01[e][0] = P * (cn[3] * cn[7]); v01[e][1] = P * (sn[3] * cn[7]);
    v01[e][2] = P * (cn[3] * sn[7]); v01[e][3] = P * (sn[3] * sn[7]);
    v23[e][0] = cn[5] * cn[1]; v23[e][1] = sn[5] * cn[1];
    v23[e][2] = cn[5] * sn[1]; v23[e][3] = sn[5] * sn[1];
  }
  v2f w[32];
#pragma unroll
  for (int s = 0; s < 16; ++s) {
    float phv = aa;
    if (s & 1) phv += kk0;
    if (s & 2) phv += kk1;
    if (s & 4) phv += kk2;
    if (s & 8) phv += kk3;
    float sp, cp;
    __sincosf(phv, &sp, &cp);  // shared by both elements
    const float e0 = v01[0][s & 3] * v23[0][s >> 2];
    const float e1 = v01[1][s & 3] * v23[1][s >> 2];
    w[s] = mk2(e0 * cp, e0 * sp);
    w[16 + s] = mk2(e1 * cp, e1 * sp);
  }
  u3_apply<3>(w, Gb + 64);           // U3(1)
  tail_common<2>(w, Gb, res);
}

// ============================ prep ==========================================
struct c2 { float r, i; };
__device__ __forceinline__ c2 cmulh(c2 a, c2 b) { return {a.r * b.r - a.i * b.i, a.r * b.i + a.i * b.r}; }
__device__ __forceinline__ c2 cmulc(c2 a, c2 b) { return {a.r * b.r + a.i * b.i, a.i * b.r - a.r * b.i}; }
__device__ __forceinline__ c2 caddh(c2 a, c2 b) { return {a.r + b.r, a.i + b.i}; }
__device__ void mat2mul(const c2 A[4], const c2 B[4], c2 C[4]) {
  C[0] = caddh(cmulh(A[0], B[0]), cmulh(A[1], B[2]));
  C[1] = caddh(cmulh(A[0], B[1]), cmulh(A[1], B[3]));
  C[2] = caddh(cmulh(A[2], B[0]), cmulh(A[3], B[2]));
  C[3] = caddh(cmulh(A[2], B[1]), cmulh(A[3], B[3]));
}
__device__ void u3m(const float* p, c2 M[4]) {
  float st, ct, sp, cp, sl, cl;
  sincosf(0.5f * p[0], &st, &ct);
  sincosf(p[1], &sp, &cp);
  sincosf(p[2], &sl, &cl);
  M[0] = {ct, 0.f};
  M[1] = {-cl * st, -sl * st};
  M[2] = {cp * st, sp * st};
  M[3] = {(cp * cl - sp * sl) * ct, (sp * cl + cp * sl) * ct};
}
__device__ void rmat(int kind, float th, c2 R[4]) {
  float s, c;
  sincosf(0.5f * th, &s, &c);
  if (kind == 0) { R[0] = {c, 0.f}; R[1] = {0.f, -s}; R[2] = {0.f, -s}; R[3] = {c, 0.f}; }
  else if (kind == 1) { R[0] = {c, 0.f}; R[1] = {-s, 0.f}; R[2] = {s, 0.f}; R[3] = {c, 0.f}; }
  else { R[0] = {c, -s}; R[1] = {0.f, 0.f}; R[2] = {0.f, 0.f}; R[3] = {c, s}; }
}
__device__ void storeM(float* dst, const c2 M[4]) {
#pragma unroll
  for (int j = 0; j < 4; ++j) { dst[2 * j] = M[j].r; dst[2 * j + 1] = M[j].i; }
}

__global__ void qcnn_prep(const float* __restrict__ crx, const float* __restrict__ u3x,
                          const float* __restrict__ cry, const float* __restrict__ u3y,
                          const float* __restrict__ crz, const float* __restrict__ u3z,
                          float* __restrict__ G) {
  const int br = threadIdx.x;
  if (br >= 3) return;
  const float* crp = (br == 0) ? crx : (br == 1) ? cry : crz;
  const float* u3p = (br == 0) ? u3x : (br == 1) ? u3y : u3z;
  float* Gb = G + br * 128;

  const int crIdx[8] = {0, 1, 2, 3, 4, 5, 6, 9};
#pragma unroll
  for (int i = 0; i < 8; ++i) {
    const float th = crp[crIdx[i]];
    float s, c;
    sincosf(0.5f * th, &s, &c);
    Gb[i * 8] = c;
    Gb[i * 8 + 1] = s;
    Gb[i * 8 + 2] = th;
    Gb[i * 8 + 3] = 0.5f * th;
  }
  c2 U1v[4], U3v[4], U5v[4], U7a[4], U7b[4], U3f[4], R[4], T[4], T2[4];
  u3m(u3p + 0, U1v);
  u3m(u3p + 3, U3v);
  u3m(u3p + 6, U5v);
  u3m(u3p + 9, U7a);
  u3m(u3p + 12, U3f);
  u3m(u3p + 15, U7b);
  storeM(Gb + 64, U1v);
  storeM(Gb + 72, U3v);
  rmat(br, crp[7], R);
  mat2mul(R, U3v, T);
  storeM(Gb + 80, T);
  storeM(Gb + 88, U5v);
  mat2mul(U7b, U7a, T);
  storeM(Gb + 96, T);
  rmat(br, crp[8], R);
  mat2mul(R, U7a, T);
  mat2mul(U7b, T, T2);
  storeM(Gb + 104, T2);
  const float n00 = U3f[0].r * U3f[0].r + U3f[0].i * U3f[0].i;
  const float n01 = U3f[1].r * U3f[1].r + U3f[1].i * U3f[1].i;
  const float n10 = U3f[2].r * U3f[2].r + U3f[2].i * U3f[2].i;
  const float n11 = U3f[3].r * U3f[3].r + U3f[3].i * U3f[3].i;
  const c2 g01 = cmulc(U3f[0], U3f[1]);
  const c2 g23 = cmulc(U3f[2], U3f[3]);
  Gb[112] = n00 - n10;
  Gb[113] = n01 - n11;
  Gb[114] = 2.f * (g01.r - g23.r);
  Gb[115] = 2.f * (g01.i - g23.i);
}

// ============================ main ==========================================
__global__ __launch_bounds__(256) void qcnn_main(
    const float* __restrict__ x, const float* __restrict__ G,
    const float* __restrict__ w1, const float* __restrict__ b1,
    const float* __restrict__ w2, const float* __restrict__ b2,
    float* __restrict__ out, int B) {
  const int gid = blockIdx.x * blockDim.x + threadIdx.x;
  const int grp = gid >> 4;  // 16-lane group, 2 interleaved elements
  const int gl = threadIdx.x & 15;
  const int b0 = grp * 2;
  if (b0 >= B) return;  // B is even; b0+1 < B whenever b0 < B
  const float* xb0 = x + b0 * 8;
  const float* xb1 = x + (b0 + 1) * 8;

  v2f fx[2], fy[2], fz[2];
  run_rx(xb0, xb1, G, gl, fx);
  run_ry(xb0, xb1, G + 128, gl, fy);
  run_rz(xb0, xb1, G + 256, gl, fz);

  // MLP head, lane-parallel over 12 hidden units; weights shared by both elems
  const int j = (gl < 12) ? gl : 0;
  const float* w1r = w1 + j * 6;
  const float w10 = w1r[0], w11 = w1r[1], w12 = w1r[2];
  const float w13 = w1r[3], w14 = w1r[4], w15 = w1r[5];
  const float b1v = b1[j], w2v = w2[j], b2v = b2[0];
  float a0 = b1v + w10 * fx[0].x + w11 * fx[0].y + w12 * fy[0].x +
             w13 * fy[0].y + w14 * fz[0].x + w15 * fz[0].y;
  float a1 = b1v + w10 * fx[1].x + w11 * fx[1].y + w12 * fy[1].x +
             w13 * fy[1].y + w14 * fz[1].x + w15 * fz[1].y;
  const float e0 = __expf(2.f * a0), e1 = __expf(2.f * a1);
  const float th0 = 1.f - 2.f * __builtin_amdgcn_rcpf(e0 + 1.f);
  const float th1 = 1.f - 2.f * __builtin_amdgcn_rcpf(e1 + 1.f);
  float t0 = (gl < 12) ? w2v * th0 : 0.f;
  float t1 = (gl < 12) ? w2v * th1 : 0.f;
  t0 += swz1<1>(t0); t1 += swz1<1>(t1);
  t0 += swz1<2>(t0); t1 += swz1<2>(t1);
  t0 += swz1<4>(t0); t1 += swz1<4>(t1);
  t0 += swz1<8>(t0); t1 += swz1<8>(t1);
  const float r0 = __builtin_amdgcn_rcpf(1.f + __expf(-(t0 + b2v)));
  const float r1 = __builtin_amdgcn_rcpf(1.f + __expf(-(t1 + b2v)));
  if (gl == 0) {
    out[b0] = r0;
    out[b0 + 1] = r1;
  }
}

extern "C" void kernel_launch(void* const* d_in, const int* in_sizes, int n_in,
                              void* d_out, int out_size, void* d_ws,
                              size_t ws_size, hipStream_t stream) {
  const float* x = (const float*)d_in[0];
  const float* crx = (const float*)d_in[1];
  const float* u3x = (const float*)d_in[2];
  const float* cry = (const float*)d_in[3];
  const float* u3y = (const float*)d_in[4];
  const float* crz = (const float*)d_in[5];
  const float* u3z = (const float*)d_in[6];
  const float* w1 = (const float*)d_in[7];
  const float* b1 = (const float*)d_in[8];
  const float* w2 = (const float*)d_in[9];
  const float* b2 = (const float*)d_in[10];
  float* out = (float*)d_out;
  float* G = (float*)d_ws;  // 384 floats
  const int B = in_sizes[0] / 8;

  hipLaunchKernelGGL(qcnn_prep, dim3(1), dim3(64), 0, stream, crx, u3x, cry,
                     u3y, crz, u3z, G);
  const int ngroups = (B + 1) / 2;  // 2 elements per 16-lane group
  const int threads = 256;
  const int blocks = (ngroups * 16 + threads - 1) / threads;
  hipLaunchKernelGGL(qcnn_main, dim3(blocks), dim3(threads), 0, stream, x, G,
                     w1, b1, w2, b2, out, B);
}

// Round 6
// 104.787 us; speedup vs baseline: 1.1019x; 1.0170x over previous
//
#include <hip/hip_runtime.h>
#include <math.h>

// ---------------------------------------------------------------------------
// QCNN_Diff R15: reduce executed VALU cycles + de-synchronize uniform-load
// stalls. Model (fits R8-R14): wave64 v_pk_*_f32 = 4 issue cycles on SIMD-32
// (128 FLOP-lanes at 32/cyc) -> pipe ~55% throughput-occupied at 4 waves/SIMD;
// lockstep waves hit the same per-gate s_load/lgkm stalls simultaneously so
// TLP can't fill them (explains R10-R14 nulls).
// Changes vs validated R14 (absmax 0.0, 106.6us):
//  1. encode sincos hoisted: 16 __sincosf + 2 float4 x-loads computed ONCE in
//     qcnn_main and passed to all three branches (was 3x redundant).
//  2. all gate-matrix ld2's clustered at branch/tail entry (one wait cluster
//     per branch instead of ~15 per-gate stalls).
// Gate math byte-identical (pure code motion). DPP for XOR-1/2 kept.
// slot bits: q3->S0 q7->S1 q5->S2 q1->S3; lane bits: q0->L0 q2->L1 q4->L2 q6->L3
// ---------------------------------------------------------------------------

typedef float v2f __attribute__((ext_vector_type(2)));

__device__ __forceinline__ v2f mk2(float a, float b) { v2f r; r.x = a; r.y = b; return r; }
__device__ __forceinline__ v2f ld2(const float* __restrict__ p) { return *(const v2f*)p; }

// ---- VOP3P primitives, VGPR x VGPR -----------------------------------------
__device__ __forceinline__ v2f pk_mul_s(v2f a, v2f b) { v2f d;
  asm("v_pk_mul_f32 %0, %1, %2 op_sel:[0,0] op_sel_hi:[0,1]" : "=v"(d) : "v"(a), "v"(b)); return d; }
__device__ __forceinline__ v2f pk_fma_irot(v2f a, v2f b, v2f c) { v2f d;
  asm("v_pk_fma_f32 %0, %1, %2, %3 op_sel:[1,1,0] op_sel_hi:[1,0,1] neg_lo:[0,1,0]" : "=v"(d) : "v"(a), "v"(b), "v"(c)); return d; }
__device__ __forceinline__ v2f cmul(v2f a, v2f b) { return pk_fma_irot(a, b, pk_mul_s(a, b)); }
__device__ __forceinline__ v2f pk_mul_swap(v2f a, v2f b) { v2f d;
  asm("v_pk_mul_f32 %0, %1, %2 op_sel:[1,0] op_sel_hi:[0,1]" : "=v"(d) : "v"(a), "v"(b)); return d; }

// ---- VOP3P primitives, SGPR (wave-uniform) first operand -------------------
__device__ __forceinline__ v2f pk_mul_sM(v2f M, v2f b) { v2f d;
  asm("v_pk_mul_f32 %0, %1, %2 op_sel:[0,0] op_sel_hi:[0,1]" : "=v"(d) : "s"(M), "v"(b)); return d; }
__device__ __forceinline__ v2f pk_fma_sloM(v2f M, v2f b, v2f c) { v2f d;
  asm("v_pk_fma_f32 %0, %1, %2, %3 op_sel:[0,0,0] op_sel_hi:[0,1,1]" : "=v"(d) : "s"(M), "v"(b), "v"(c)); return d; }
__device__ __forceinline__ v2f pk_fma_shiM(v2f M, v2f b, v2f c) { v2f d;
  asm("v_pk_fma_f32 %0, %1, %2, %3 op_sel:[1,0,0] op_sel_hi:[1,1,1]" : "=v"(d) : "s"(M), "v"(b), "v"(c)); return d; }
__device__ __forceinline__ v2f pk_fma_shi_negM(v2f M, v2f b, v2f c) { v2f d;
  asm("v_pk_fma_f32 %0, %1, %2, %3 op_sel:[1,0,0] op_sel_hi:[1,1,1] neg_lo:[1,0,0] neg_hi:[1,0,0]" : "=v"(d) : "s"(M), "v"(b), "v"(c)); return d; }
__device__ __forceinline__ v2f pk_fma_rotM(v2f M, v2f b, v2f c) { v2f d;
  asm("v_pk_fma_f32 %0, %1, %2, %3 op_sel:[1,1,0] op_sel_hi:[1,0,1] neg_hi:[0,1,0]" : "=v"(d) : "s"(M), "v"(b), "v"(c)); return d; }
__device__ __forceinline__ v2f pk_fma_irotM(v2f M, v2f b, v2f c) { v2f d;
  asm("v_pk_fma_f32 %0, %1, %2, %3 op_sel:[1,1,0] op_sel_hi:[1,0,1] neg_lo:[0,1,0]" : "=v"(d) : "s"(M), "v"(b), "v"(c)); return d; }

// ---- cross-lane: DPP quad_perm for XOR 1/2 (VALU), ds_swizzle for 4/8 ------
template <int MASK>
__device__ __forceinline__ float swz1(float v) {
  if constexpr (MASK == 1) {
    return __int_as_float(__builtin_amdgcn_update_dpp(
        0, __float_as_int(v), 0xB1, 0xF, 0xF, true));  // quad_perm [1,0,3,2]
  } else if constexpr (MASK == 2) {
    return __int_as_float(__builtin_amdgcn_update_dpp(
        0, __float_as_int(v), 0x4E, 0xF, 0xF, true));  // quad_perm [2,3,0,1]
  } else {
    constexpr int pat = (MASK << 10) | 0x1F;  // xor-mode ds_swizzle
    return __int_as_float(__builtin_amdgcn_ds_swizzle(__float_as_int(v), pat));
  }
}
template <int MASK>
__device__ __forceinline__ v2f swz2(v2f v) {
  v2f r; r.x = swz1<MASK>(v.x); r.y = swz1<MASK>(v.y); return r;
}

// ---- u3 row: ua*a + ub*b, matrices from SGPRs ------------------------------
template <bool A_REAL>
__device__ __forceinline__ v2f u3row_s(v2f ua, v2f ub, v2f a, v2f b) {
  v2f t = pk_mul_sM(ua, a);
  if constexpr (!A_REAL) t = pk_fma_irotM(ua, a, t);
  t = pk_fma_sloM(ub, b, t);
  return pk_fma_irotM(ub, b, t);
}

// All gate helpers operate on w[32] = two interleaved elements; slot-pair
// bits are the low 4 index bits, element = bit 4, so i|(1<<SB) stays in-element.
// Matrix operands are passed as preloaded v2f values (clustered loads).
template <int SB>
__device__ __forceinline__ void u3_applyv(v2f w[32], v2f M0, v2f M1, v2f M2,
                                          v2f M3) {
#pragma unroll
  for (int i = 0; i < 32; ++i) {
    if (i & (1 << SB)) continue;
    const int i1 = i | (1 << SB);
    const v2f a = w[i], b = w[i1];
    w[i] = u3row_s<true>(M0, M1, a, b);
    w[i1] = u3row_s<false>(M3, M2, b, a);
  }
}

template <int SB, int CB, bool M00R>
__device__ __forceinline__ void u3_selv(v2f w[32], v2f M0, v2f M1, v2f M2,
                                        v2f M3, v2f N0, v2f N1, v2f N2, v2f N3) {
#pragma unroll
  for (int i = 0; i < 32; ++i) {
    if (i & (1 << SB)) continue;
    const int i1 = i | (1 << SB);
    const v2f a = w[i], b = w[i1];
    if ((i >> CB) & 1) {
      w[i] = u3row_s<false>(N0, N1, a, b);
      w[i1] = u3row_s<false>(N3, N2, b, a);
    } else {
      w[i] = u3row_s<M00R>(M0, M1, a, b);
      w[i1] = u3row_s<false>(M3, M2, b, a);
    }
  }
}

template <int SB, int LB>
__device__ __forceinline__ void crx_Sc_Lt(v2f w[32], v2f cs) {
#pragma unroll
  for (int i = 0; i < 32; ++i) {
    if (!(i & (1 << SB))) continue;
    const v2f p = swz2<(1 << LB)>(w[i]);
    w[i] = pk_fma_rotM(cs, p, pk_mul_sM(cs, w[i]));
  }
}

template <int SB, int LB>
__device__ __forceinline__ void cr_ry_r(float w[32], v2f cs, int gl) {
  const bool tb = (gl >> LB) & 1;
  const float Ky = tb ? cs.y : -cs.y;
#pragma unroll
  for (int i = 0; i < 32; ++i) {
    if (!(i & (1 << SB))) continue;
    const float p = swz1<(1 << LB)>(w[i]);
    w[i] = __builtin_fmaf(Ky, p, cs.x * w[i]);
  }
}

template <int KIND, int SBc, int SBt>
__device__ __forceinline__ void cr_Sc_St(v2f w[32], v2f cs) {
#pragma unroll
  for (int i = 0; i < 32; ++i) {
    if (!(i & (1 << SBc))) continue;
    if constexpr (KIND == 2) {
      const v2f t = pk_mul_sM(cs, w[i]);
      w[i] = (i & (1 << SBt)) ? pk_fma_irotM(cs, w[i], t)
                              : pk_fma_rotM(cs, w[i], t);
    } else {
      if (i & (1 << SBt)) continue;
      const int i1 = i | (1 << SBt);
      const v2f a = w[i], b = w[i1];
      if constexpr (KIND == 0) {
        w[i] = pk_fma_rotM(cs, b, pk_mul_sM(cs, a));
        w[i1] = pk_fma_rotM(cs, a, pk_mul_sM(cs, b));
      } else {
        w[i] = pk_fma_shi_negM(cs, b, pk_mul_sM(cs, a));
        w[i1] = pk_fma_shiM(cs, a, pk_mul_sM(cs, b));
      }
    }
  }
}

template <int SB>
__device__ __forceinline__ void u3_liftv(v2f w[32], const float wr[32], v2f M0,
                                         v2f M1, v2f M2, v2f M3) {
#pragma unroll
  for (int i = 0; i < 32; ++i) {
    if (i & (1 << SB)) continue;
    const int i1 = i | (1 << SB);
    const float a = wr[i], b = wr[i1];
    w[i] = mk2(__builtin_fmaf(a, M0.x, b * M1.x), b * M1.y);
    w[i1] = mk2(__builtin_fmaf(a, M2.x, b * M3.x),
                __builtin_fmaf(a, M2.y, b * M3.y));
  }
}

__device__ __forceinline__ void measure2v(v2f w[32], v2f qa, v2f qg,
                                          v2f res[2]) {
  float z3[2], z7[2];
#pragma unroll
  for (int e = 0; e < 2; ++e) {
    float z3a = 0.f, z3b = 0.f, z7p = 0.f, z7m = 0.f;
#pragma unroll
    for (int s0 = 0; s0 < 16; s0 += 2) {
      const v2f a = w[e * 16 + s0], b = w[e * 16 + s0 + 1];
      const v2f t1 = a * b, t2 = pk_mul_swap(a, b), t3 = a * a, t4 = b * b;
      const float r = t1.x + t1.y;
      const float m = t2.x - t2.y;
      const float na = t3.x + t3.y;
      const float nb = t4.x + t4.y;
      z3a = __builtin_fmaf(qa.x, na, z3a);
      z3b = __builtin_fmaf(qa.y, nb, z3b);
      z3a = __builtin_fmaf(qg.x, r, z3a);
      z3b = __builtin_fmaf(-qg.y, m, z3b);
      const float nn = na + nb;
      if (s0 & 2) z7m += nn; else z7p += nn;
    }
    z3[e] = z3a + z3b;
    z7[e] = z7p - z7m;
  }
  z3[0] += swz1<1>(z3[0]); z3[1] += swz1<1>(z3[1]); z7[0] += swz1<1>(z7[0]); z7[1] += swz1<1>(z7[1]);
  z3[0] += swz1<2>(z3[0]); z3[1] += swz1<2>(z3[1]); z7[0] += swz1<2>(z7[0]); z7[1] += swz1<2>(z7[1]);
  z3[0] += swz1<4>(z3[0]); z3[1] += swz1<4>(z3[1]); z7[0] += swz1<4>(z7[0]); z7[1] += swz1<4>(z7[1]);
  z3[0] += swz1<8>(z3[0]); z3[1] += swz1<8>(z3[1]); z7[0] += swz1<8>(z7[0]); z7[1] += swz1<8>(z7[1]);
  res[0] = mk2(z3[0], z7[0]);
  res[1] = mk2(z3[1], z7[1]);
}

template <int KIND>
__device__ __forceinline__ void tail_common(v2f w[32], const float* __restrict__ Gb,
                                            v2f res[2]) {
  // Clustered uniform loads: one wait group instead of per-gate stalls.
  const v2f cs35 = ld2(Gb + 56);
  const v2f A0 = ld2(Gb + 72), A1 = ld2(Gb + 74), A2 = ld2(Gb + 76), A3 = ld2(Gb + 78);
  const v2f B0 = ld2(Gb + 80), B1 = ld2(Gb + 82), B2 = ld2(Gb + 84), B3 = ld2(Gb + 86);
  const v2f C0 = ld2(Gb + 88), C1 = ld2(Gb + 90), C2 = ld2(Gb + 92), C3 = ld2(Gb + 94);
  const v2f D0 = ld2(Gb + 96), D1 = ld2(Gb + 98), D2 = ld2(Gb + 100), D3 = ld2(Gb + 102);
  const v2f E0 = ld2(Gb + 104), E1 = ld2(Gb + 106), E2 = ld2(Gb + 108), E3 = ld2(Gb + 110);
  const v2f qa = ld2(Gb + 112), qg = ld2(Gb + 114);

  u3_selv<0, 3, true>(w, A0, A1, A2, A3, B0, B1, B2, B3);  // U3first(3)/R13.U3first(3)
  u3_applyv<2>(w, C0, C1, C2, C3);                         // U3(5)
  u3_selv<1, 2, false>(w, D0, D1, D2, D3, E0, E1, E2, E3); // Uf7.U7 / Uf7.R57.U7
  cr_Sc_St<KIND, 0, 2>(w, cs35);                           // CR(3,5)
  measure2v(w, qa, qg, res);                               // folds U3final(3)
}

__device__ __forceinline__ void load_sincos(const float* __restrict__ xb,
                                            float sn[8], float cn[8]) {
  const float4 xlo = ((const float4*)xb)[0];
  const float4 xhi = ((const float4*)xb)[1];
  const float xq[8] = {xlo.x, xlo.y, xlo.z, xlo.w, xhi.x, xhi.y, xhi.z, xhi.w};
#pragma unroll
  for (int q = 0; q < 8; ++q) __sincosf(0.5f * xq[q], &sn[q], &cn[q]);
}

// ============================ branch heads ==================================
// sn/cn: shared encode sincos, computed once in qcnn_main (was 3x redundant).
__device__ __forceinline__ void run_rx(const float sn[2][8], const float cn[2][8],
                                       const float* __restrict__ Gb, int gl,
                                       v2f res[2]) {
  const bool l0 = gl & 1, l1 = (gl >> 1) & 1, l2 = (gl >> 2) & 1, l3 = (gl >> 3) & 1;
  const v2f cp[4] = {ld2(Gb), ld2(Gb + 8), ld2(Gb + 16), ld2(Gb + 24)};
  const v2f cs12 = ld2(Gb + 32), cs34 = ld2(Gb + 40), cs56 = ld2(Gb + 48);
  const v2f U0 = ld2(Gb + 64), U1 = ld2(Gb + 66), U2 = ld2(Gb + 68), U3 = ld2(Gb + 70);
  v2f w[32];
#pragma unroll
  for (int e = 0; e < 2; ++e) {
    v2f pa[4], pb[4];
#pragma unroll
    for (int pr = 0; pr < 4; ++pr) {
      const bool lh = (pr == 0) ? l0 : (pr == 1) ? l1 : (pr == 2) ? l2 : l3;
      const float c = cp[pr].x, s = cp[pr].y;
      const float uc = lh ? sn[e][2 * pr] : cn[e][2 * pr];
      const float b0 = uc * cn[e][2 * pr + 1], b1 = uc * sn[e][2 * pr + 1];
      const float Kx = lh ? c : 1.f;
      const float Kyn = lh ? -s : 0.f;
      pa[pr] = mk2(Kx * b0, Kyn * b1);
      pb[pr] = mk2(Kx * b1, Kyn * b0);
    }
    v2f A[4] = {cmul(pa[0], pa[2]), cmul(pa[0], pb[2]), cmul(pb[0], pa[2]), cmul(pb[0], pb[2])};
    v2f Bv[4] = {cmul(pa[3], pa[1]), cmul(pa[3], pb[1]), cmul(pb[3], pa[1]), cmul(pb[3], pb[1])};
#pragma unroll
    for (int s = 0; s < 16; ++s) w[e * 16 + s] = cmul(A[s >> 2], Bv[s & 3]);
  }
  crx_Sc_Lt<3, 1>(w, cs12);  // (1,2)  -> DPP path (mask 2)
  crx_Sc_Lt<0, 2>(w, cs34);  // (3,4)  -> ds_swizzle (mask 4)
  crx_Sc_Lt<2, 3>(w, cs56);  // (5,6)  -> ds_swizzle (mask 8)
  u3_applyv<3>(w, U0, U1, U2, U3);  // U3(1)
  tail_common<0>(w, Gb, res);
}

__device__ __forceinline__ void run_ry(const float sn[2][8], const float cn[2][8],
                                       const float* __restrict__ Gb, int gl,
                                       v2f res[2]) {
  const bool l0 = gl & 1, l1 = (gl >> 1) & 1, l2 = (gl >> 2) & 1, l3 = (gl >> 3) & 1;
  const v2f cp[4] = {ld2(Gb), ld2(Gb + 8), ld2(Gb + 16), ld2(Gb + 24)};
  const v2f cs12 = ld2(Gb + 32), cs34 = ld2(Gb + 40), cs56 = ld2(Gb + 48);
  const v2f U0 = ld2(Gb + 64), U1 = ld2(Gb + 66), U2 = ld2(Gb + 68), U3 = ld2(Gb + 70);
  float wr[32];
#pragma unroll
  for (int e = 0; e < 2; ++e) {
    float pa[4], pb[4];
#pragma unroll
    for (int pr = 0; pr < 4; ++pr) {
      const bool lh = (pr == 0) ? l0 : (pr == 1) ? l1 : (pr == 2) ? l2 : l3;
      const float c = cp[pr].x, s = cp[pr].y;
      const float uc = lh ? sn[e][2 * pr] : cn[e][2 * pr];
      const float b0 = uc * cn[e][2 * pr + 1], b1 = uc * sn[e][2 * pr + 1];
      const float Kx = lh ? c : 1.f;
      const float Ky = lh ? s : 0.f;
      pa[pr] = Kx * b0 - Ky * b1;
      pb[pr] = Ky * b0 + Kx * b1;
    }
    const float A[4] = {pa[0] * pa[2], pa[0] * pb[2], pb[0] * pa[2], pb[0] * pb[2]};
    const float Bv[4] = {pa[3] * pa[1], pa[3] * pb[1], pb[3] * pa[1], pb[3] * pb[1]};
#pragma unroll
    for (int s = 0; s < 16; ++s) wr[e * 16 + s] = A[s >> 2] * Bv[s & 3];
  }
  cr_ry_r<3, 1>(wr, cs12, gl);  // mask 2 -> DPP
  cr_ry_r<0, 2>(wr, cs34, gl);  // mask 4 -> DS
  cr_ry_r<2, 3>(wr, cs56, gl);  // mask 8 -> DS
  v2f w[32];
  u3_liftv<3>(w, wr, U0, U1, U2, U3);  // U3(1), real input
  tail_common<1>(w, Gb, res);
}

__device__ __forceinline__ void run_rz(const float sn[2][8], const float cn[2][8],
                                       const float* __restrict__ Gb, int gl,
                                       v2f res[2]) {
  const bool l0 = gl & 1, l1 = (gl >> 1) & 1, l2 = (gl >> 2) & 1, l3 = (gl >> 3) & 1;
  // shared phase coefficients (element-independent)
  const float t0 = Gb[2], h0 = Gb[3];
  const float t1 = Gb[10], h1 = Gb[11];
  const float t2 = Gb[18], h2 = Gb[19];
  const float t3 = Gb[26], h3 = Gb[27];
  const float h4 = Gb[35], h5 = Gb[43], h6 = Gb[51];
  const v2f U0 = ld2(Gb + 64), U1 = ld2(Gb + 66), U2 = ld2(Gb + 68), U3 = ld2(Gb + 70);
  const float kk0 = (l1 ? t1 : 0.f) + (l2 ? h5 : -h5);
  const float kk1 = (l3 ? t3 : 0.f);
  const float kk2 = (l2 ? t2 : 0.f) + (l3 ? h6 : -h6);
  const float kk3 = (l0 ? t0 : 0.f) + (l1 ? h4 : -h4);
  const float aa = -((l0 ? h0 : 0.f) + (l1 ? h1 : 0.f) + (l2 ? h2 : 0.f) + (l3 ? h3 : 0.f));
  // per-element real envelopes
  float v01[2][4], v23[2][4];
#pragma unroll
  for (int e = 0; e < 2; ++e) {
    const float u0 = l0 ? sn[e][0] : cn[e][0];
    const float u2 = l1 ? sn[e][2] : cn[e][2];
    const float u4 = l2 ? sn[e][4] : cn[e][4];
    const float u6 = l3 ? sn[e][6] : cn[e][6];
    const float P = (u0 * u2) * (u4 * u6);
    v01[e][0] = P * (cn[e][3] * cn[e][7]); v01[e][1] = P * (sn[e][3] * cn[e][7]);
    v01[e][2] = P * (cn[e][3] * sn[e][7]); v01[e][3] = P * (sn[e][3] * sn[e][7]);
    v23[e][0] = cn[e][5] * cn[e][1]; v23[e][1] = sn[e][5] * cn[e][1];
    v23[e][2] = cn[e][5] * sn[e][1]; v23[e][3] = sn[e][5] * sn[e][1];
  }
  v2f w[32];
#pragma unroll
  for (int s = 0; s < 16; ++s) {
    float phv = aa;
    if (s & 1) phv += kk0;
    if (s & 2) phv += kk1;
    if (s & 4) phv += kk2;
    if (s & 8) phv += kk3;
    float sp, cp;
    __sincosf(phv, &sp, &cp);  // shared by both elements
    const float e0 = v01[0][s & 3] * v23[0][s >> 2];
    const float e1 = v01[1][s & 3] * v23[1][s >> 2];
    w[s] = mk2(e0 * cp, e0 * sp);
    w[16 + s] = mk2(e1 * cp, e1 * sp);
  }
  u3_applyv<3>(w, U0, U1, U2, U3);  // U3(1)
  tail_common<2>(w, Gb, res);
}

// ============================ prep ==========================================
struct c2 { float r, i; };
__device__ __forceinline__ c2 cmulh(c2 a, c2 b) { return {a.r * b.r - a.i * b.i, a.r * b.i + a.i * b.r}; }
__device__ __forceinline__ c2 cmulc(c2 a, c2 b) { return {a.r * b.r + a.i * b.i, a.i * b.r - a.r * b.i}; }
__device__ __forceinline__ c2 caddh(c2 a, c2 b) { return {a.r + b.r, a.i + b.i}; }
__device__ void mat2mul(const c2 A[4], const c2 B[4], c2 C[4]) {
  C[0] = caddh(cmulh(A[0], B[0]), cmulh(A[1], B[2]));
  C[1] = caddh(cmulh(A[0], B[1]), cmulh(A[1], B[3]));
  C[2] = caddh(cmulh(A[2], B[0]), cmulh(A[3], B[2]));
  C[3] = caddh(cmulh(A[2], B[1]), cmulh(A[3], B[3]));
}
__device__ void u3m(const float* p, c2 M[4]) {
  float st, ct, sp, cp, sl, cl;
  sincosf(0.5f * p[0], &st, &ct);
  sincosf(p[1], &sp, &cp);
  sincosf(p[2], &sl, &cl);
  M[0] = {ct, 0.f};
  M[1] = {-cl * st, -sl * st};
  M[2] = {cp * st, sp * st};
  M[3] = {(cp * cl - sp * sl) * ct, (sp * cl + cp * sl) * ct};
}
__device__ void rmat(int kind, float th, c2 R[4]) {
  float s, c;
  sincosf(0.5f * th, &s, &c);
  if (kind == 0) { R[0] = {c, 0.f}; R[1] = {0.f, -s}; R[2] = {0.f, -s}; R[3] = {c, 0.f}; }
  else if (kind == 1) { R[0] = {c, 0.f}; R[1] = {-s, 0.f}; R[2] = {s, 0.f}; R[3] = {c, 0.f}; }
  else { R[0] = {c, -s}; R[1] = {0.f, 0.f}; R[2] = {0.f, 0.f}; R[3] = {c, s}; }
}
__device__ void storeM(float* dst, const c2 M[4]) {
#pragma unroll
  for (int j = 0; j < 4; ++j) { dst[2 * j] = M[j].r; dst[2 * j + 1] = M[j].i; }
}

__global__ void qcnn_prep(const float* __restrict__ crx, const float* __restrict__ u3x,
                          const float* __restrict__ cry, const float* __restrict__ u3y,
                          const float* __restrict__ crz, const float* __restrict__ u3z,
                          float* __restrict__ G) {
  const int br = threadIdx.x;
  if (br >= 3) return;
  const float* crp = (br == 0) ? crx : (br == 1) ? cry : crz;
  const float* u3p = (br == 0) ? u3x : (br == 1) ? u3y : u3z;
  float* Gb = G + br * 128;

  const int crIdx[8] = {0, 1, 2, 3, 4, 5, 6, 9};
#pragma unroll
  for (int i = 0; i < 8; ++i) {
    const float th = crp[crIdx[i]];
    float s, c;
    sincosf(0.5f * th, &s, &c);
    Gb[i * 8] = c;
    Gb[i * 8 + 1] = s;
    Gb[i * 8 + 2] = th;
    Gb[i * 8 + 3] = 0.5f * th;
  }
  c2 U1v[4], U3v[4], U5v[4], U7a[4], U7b[4], U3f[4], R[4], T[4], T2[4];
  u3m(u3p + 0, U1v);
  u3m(u3p + 3, U3v);
  u3m(u3p + 6, U5v);
  u3m(u3p + 9, U7a);
  u3m(u3p + 12, U3f);
  u3m(u3p + 15, U7b);
  storeM(Gb + 64, U1v);
  storeM(Gb + 72, U3v);
  rmat(br, crp[7], R);
  mat2mul(R, U3v, T);
  storeM(Gb + 80, T);
  storeM(Gb + 88, U5v);
  mat2mul(U7b, U7a, T);
  storeM(Gb + 96, T);
  rmat(br, crp[8], R);
  mat2mul(R, U7a, T);
  mat2mul(U7b, T, T2);
  storeM(Gb + 104, T2);
  const float n00 = U3f[0].r * U3f[0].r + U3f[0].i * U3f[0].i;
  const float n01 = U3f[1].r * U3f[1].r + U3f[1].i * U3f[1].i;
  const float n10 = U3f[2].r * U3f[2].r + U3f[2].i * U3f[2].i;
  const float n11 = U3f[3].r * U3f[3].r + U3f[3].i * U3f[3].i;
  const c2 g01 = cmulc(U3f[0], U3f[1]);
  const c2 g23 = cmulc(U3f[2], U3f[3]);
  Gb[112] = n00 - n10;
  Gb[113] = n01 - n11;
  Gb[114] = 2.f * (g01.r - g23.r);
  Gb[115] = 2.f * (g01.i - g23.i);
}

// ============================ main ==========================================
__global__ __launch_bounds__(256) void qcnn_main(
    const float* __restrict__ x, const float* __restrict__ G,
    const float* __restrict__ w1, const float* __restrict__ b1,
    const float* __restrict__ w2, const float* __restrict__ b2,
    float* __restrict__ out, int B) {
  const int gid = blockIdx.x * blockDim.x + threadIdx.x;
  const int grp = gid >> 4;  // 16-lane group, 2 interleaved elements
  const int gl = threadIdx.x & 15;
  const int b0 = grp * 2;
  if (b0 >= B) return;  // B is even; b0+1 < B whenever b0 < B

  // Shared encode sincos: once per element, reused by all three branches.
  float sn[2][8], cn[2][8];
  load_sincos(x + b0 * 8, sn[0], cn[0]);
  load_sincos(x + (b0 + 1) * 8, sn[1], cn[1]);

  v2f fx[2], fy[2], fz[2];
  run_rx(sn, cn, G, gl, fx);
  run_ry(sn, cn, G + 128, gl, fy);
  run_rz(sn, cn, G + 256, gl, fz);

  // MLP head, lane-parallel over 12 hidden units; weights shared by both elems
  const int j = (gl < 12) ? gl : 0;
  const float* w1r = w1 + j * 6;
  const float w10 = w1r[0], w11 = w1r[1], w12 = w1r[2];
  const float w13 = w1r[3], w14 = w1r[4], w15 = w1r[5];
  const float b1v = b1[j], w2v = w2[j], b2v = b2[0];
  float a0 = b1v + w10 * fx[0].x + w11 * fx[0].y + w12 * fy[0].x +
             w13 * fy[0].y + w14 * fz[0].x + w15 * fz[0].y;
  float a1 = b1v + w10 * fx[1].x + w11 * fx[1].y + w12 * fy[1].x +
             w13 * fy[1].y + w14 * fz[1].x + w15 * fz[1].y;
  const float e0 = __expf(2.f * a0), e1 = __expf(2.f * a1);
  const float th0 = 1.f - 2.f * __builtin_amdgcn_rcpf(e0 + 1.f);
  const float th1 = 1.f - 2.f * __builtin_amdgcn_rcpf(e1 + 1.f);
  float t0 = (gl < 12) ? w2v * th0 : 0.f;
  float t1 = (gl < 12) ? w2v * th1 : 0.f;
  t0 += swz1<1>(t0); t1 += swz1<1>(t1);
  t0 += swz1<2>(t0); t1 += swz1<2>(t1);
  t0 += swz1<4>(t0); t1 += swz1<4>(t1);
  t0 += swz1<8>(t0); t1 += swz1<8>(t1);
  const float r0 = __builtin_amdgcn_rcpf(1.f + __expf(-(t0 + b2v)));
  const float r1 = __builtin_amdgcn_rcpf(1.f + __expf(-(t1 + b2v)));
  if (gl == 0) {
    out[b0] = r0;
    out[b0 + 1] = r1;
  }
}

extern "C" void kernel_launch(void* const* d_in, const int* in_sizes, int n_in,
                              void* d_out, int out_size, void* d_ws,
                              size_t ws_size, hipStream_t stream) {
  const float* x = (const float*)d_in[0];
  const float* crx = (const float*)d_in[1];
  const float* u3x = (const float*)d_in[2];
  const float* cry = (const float*)d_in[3];
  const float* u3y = (const float*)d_in[4];
  const float* crz = (const float*)d_in[5];
  const float* u3z = (const float*)d_in[6];
  const float* w1 = (const float*)d_in[7];
  const float* b1 = (const float*)d_in[8];
  const float* w2 = (const float*)d_in[9];
  const float* b2 = (const float*)d_in[10];
  float* out = (float*)d_out;
  float* G = (float*)d_ws;  // 384 floats
  const int B = in_sizes[0] / 8;

  hipLaunchKernelGGL(qcnn_prep, dim3(1), dim3(64), 0, stream, crx, u3x, cry,
                     u3y, crz, u3z, G);
  const int ngroups = (B + 1) / 2;  // 2 elements per 16-lane group
  const int threads = 256;
  const int blocks = (ngroups * 16 + threads - 1) / threads;
  hipLaunchKernelGGL(qcnn_main, dim3(blocks), dim3(threads), 0, stream, x, G,
                     w1, b1, w2, b2, out, B);
}